// Round 5
// baseline (531.988 us; speedup 1.0000x reference)
//
#include <hip/hip_runtime.h>
#include <hip/hip_bf16.h>
#include <math.h>

typedef __attribute__((ext_vector_type(4))) float f32x4;
typedef __attribute__((ext_vector_type(8))) short s16x8;
typedef __attribute__((ext_vector_type(4))) short s16x4;

#define BB 4
#define TT 2048
#define CC 2048
#define NHEAD 16
#define KVH 4
#define HD 128
#define BT (BB*TT)      // 8192
#define NHC 2048        // N*H
#define KHC 512         // K*H
#define QKVC 3072

__device__ __forceinline__ float bf2f(unsigned short u) {
  union { unsigned u; float f; } v; v.u = ((unsigned)u) << 16; return v.f;
}
__device__ __forceinline__ unsigned short f2bf(float f) {
  union { float f; unsigned u; } v; v.f = f;
  unsigned r = v.u + 0x7fff + ((v.u >> 16) & 1);
  return (unsigned short)(r >> 16);
}

#if defined(__has_builtin)
#if __has_builtin(__builtin_amdgcn_exp2f)
#define EXP2F(x) __builtin_amdgcn_exp2f(x)
#endif
#endif
#ifndef EXP2F
#define EXP2F(x) exp2f(x)
#endif

// ---- async global->LDS 16B (lane i lands at ldsbase + i*16; ldsbase must be wave-uniform) ----
__device__ __forceinline__ void glld16(const void* gsrc, void* ldsbase) {
  __builtin_amdgcn_global_load_lds(
      (const __attribute__((address_space(1))) unsigned int*)gsrc,
      (__attribute__((address_space(3))) unsigned int*)(unsigned int)(unsigned long long)ldsbase,
      16, 0, 0);
}

// ---- opaque LDS b128 read: compiler cannot see the LDS dependency, so it
// cannot insert its own vmcnt(0) drain before it (we order manually). ----
__device__ __forceinline__ s16x8 lds_read_b128(unsigned addr) {
  s16x8 r;
  asm volatile("ds_read_b128 %0, %1" : "=v"(r) : "v"(addr));
  return r;
}

// ---------------- fp32 -> bf16 elementwise ----------------
__global__ void cvt_f2b(const float* __restrict__ in, unsigned short* __restrict__ out, int n4) {
  int i = blockIdx.x * 256 + threadIdx.x;
  if (i >= n4) return;
  float4 v = ((const float4*)in)[i];
  ushort4 o;
  o.x = f2bf(v.x); o.y = f2bf(v.y); o.z = f2bf(v.z); o.w = f2bf(v.w);
  ((ushort4*)out)[i] = o;
}

// ---------------- fp32 [R][Cc] -> bf16 [Cc][R] transpose ----------------
__global__ void trans_f2b(const float* __restrict__ in, unsigned short* __restrict__ out, int R, int Cc) {
  __shared__ float tile[32][33];
  int c0 = blockIdx.x * 32, r0 = blockIdx.y * 32;
  int tx = threadIdx.x, ty = threadIdx.y;
  #pragma unroll
  for (int k = 0; k < 4; k++)
    tile[ty + 8*k][tx] = in[(size_t)(r0 + ty + 8*k) * Cc + c0 + tx];
  __syncthreads();
  #pragma unroll
  for (int k = 0; k < 4; k++)
    out[(size_t)(c0 + ty + 8*k) * R + r0 + tx] = f2bf(tile[tx][ty + 8*k]);
}

// ---------------- V slice transpose bf16 [s][h] -> [h][s] ----------------
__global__ void trans_v(const unsigned short* __restrict__ qkv, unsigned short* __restrict__ vT) {
  __shared__ unsigned short tile[32][33];
  int slice = blockIdx.z;           // b*4+kh
  int s0 = blockIdx.x * 32, h0 = blockIdx.y * 32;
  int tx = threadIdx.x, ty = threadIdx.y;
  const unsigned short* in = qkv + (size_t)(slice >> 2) * TT * QKVC + (NHC + KHC) + (slice & 3) * HD;
  unsigned short* out = vT + (size_t)slice * HD * TT;
  #pragma unroll
  for (int k = 0; k < 4; k++)
    tile[ty + 8*k][tx] = in[(size_t)(s0 + ty + 8*k) * QKVC + h0 + tx];
  __syncthreads();
  #pragma unroll
  for (int k = 0; k < 4; k++)
    out[(size_t)(h0 + ty + 8*k) * TT + s0 + tx] = tile[tx][ty + 8*k];
}

// ---------------- RoPE sin/cos table (fp64 precision) ----------------
__global__ void sincos_init(float* __restrict__ stab, float* __restrict__ ctab) {
  int idx = blockIdx.x * 256 + threadIdx.x;
  if (idx >= TT * 64) return;
  int t = idx >> 6, i = idx & 63;
  double inv = exp(-log(10000.0) * ((double)i / 64.0));
  double ang = (double)t * inv;
  stab[idx] = (float)sin(ang);
  ctab[idx] = (float)cos(ang);
}

// ---------------- NT GEMM 256x256, BK=32, 8 waves, depth-3 ring + ASM ds_read ----------------
// Round-5 change: fragment loads are inline-asm ds_read_b128 (opaque to the
// compiler's aliasing/waitcnt pass) so the counted vmcnt(8) actually keeps
// tiles t+1/t+2 in flight across the barrier instead of being pre-drained by
// a compiler-inserted vmcnt(0). Each K-tile = 2 fine-interleaved phases:
// {stage-half(t+3) | asm ds_read | lgkmcnt(0)+sched_barrier | 16 MFMA}.
// Ordering is manual: per-wave vmcnt(4*tiles_ahead) + raw s_barrier at tile
// top => tile t's LDS writes landed in ALL waves; stage targets buf (t+3)&3
// == (t-1)&3 whose reads finished before that same barrier.
template<int OUTBF16>
__global__ __launch_bounds__(512, 2) void gemm256(
    const unsigned short* __restrict__ A, const unsigned short* __restrict__ Bt,
    void* __restrict__ outp, int M, int Nn, int Kd) {
  __shared__ unsigned short As[4][256 * 32];   // 16 KiB per buf
  __shared__ unsigned short Bs[4][256 * 32];
  int tid = threadIdx.x;
  int wave = tid >> 6, lane = tid & 63, q4 = lane >> 4, l16 = lane & 15;

  int gx = Nn >> 8;
  int nwg = gridDim.x;
  int bid = blockIdx.x;
  int bid2 = (nwg & 7) ? bid : ((bid & 7) * (nwg >> 3) + (bid >> 3));
  int bx = bid2 % gx, by = bid2 / gx;
  int m0 = by * 256, n0 = bx * 256;

  int wm = (wave >> 2) * 128;      // 2 M-waves
  int wn = (wave & 3) * 64;        // 4 N-waves

  f32x4 acc[8][4];
  #pragma unroll
  for (int i = 0; i < 8; i++)
    #pragma unroll
    for (int j = 0; j < 4; j++) acc[i][j] = f32x4{0.f, 0.f, 0.f, 0.f};

  const unsigned short* Abase = A + (size_t)m0 * Kd;
  const unsigned short* Bbase = Bt + (size_t)n0 * Kd;

  // stage source geometry (verified round 4): LDS chunk L = rd*512+wave*64+lane;
  // srow=L>>3, eff=L&7; slot8=eff^(srow&7); row=srow*2+(slot8>>2); kchunk=slot8&3.
  int sR[2], sCG[2], sBase[2];
  #pragma unroll
  for (int rd = 0; rd < 2; rd++) {
    int L = rd * 512 + wave * 64 + lane;
    int srow = L >> 3, eff = L & 7;
    int slot8 = eff ^ (srow & 7);
    sR[rd] = srow * 2 + (slot8 >> 2);
    sCG[rd] = slot8 & 3;
    sBase[rd] = (rd * 512 + wave * 64) * 8;   // wave-uniform LDS short offset
  }
  auto stageA = [&](int kt, int buf) {
    const unsigned short* Ak = Abase + kt * 32;
    #pragma unroll
    for (int rd = 0; rd < 2; rd++)
      glld16(Ak + (size_t)sR[rd] * Kd + sCG[rd] * 8, &As[buf][sBase[rd]]);
  };
  auto stageB = [&](int kt, int buf) {
    const unsigned short* Bk = Bbase + kt * 32;
    #pragma unroll
    for (int rd = 0; rd < 2; rd++)
      glld16(Bk + (size_t)sR[rd] * Kd + sCG[rd] * 8, &Bs[buf][sBase[rd]]);
  };

  // fragment read BYTE offsets (verified round 4), constant per thread
  int aoffB[8], boffB[4];
  #pragma unroll
  for (int mf = 0; mf < 8; mf++) {
    int R = wm + mf * 16 + l16;
    int srow = R >> 1;
    aoffB[mf] = (srow * 8 + ((((R & 1) << 2) | q4) ^ (srow & 7))) * 16;
  }
  #pragma unroll
  for (int nf = 0; nf < 4; nf++) {
    int R = wn + nf * 16 + l16;
    int srow = R >> 1;
    boffB[nf] = (srow * 8 + ((((R & 1) << 2) | q4) ^ (srow & 7))) * 16;
  }

  int nkt = Kd >> 5;              // 64 for both calls
  stageA(0, 0); stageB(0, 0);
  stageA(1, 1); stageB(1, 1);
  stageA(2, 2); stageB(2, 2);

  for (int t = 0; t < nkt; t++) {
    int cur = t & 3;
    int rem = nkt - 1 - t;
    // counted wait: tile t landed; tiles t+1/t+2 (8 loads/wave) stay in flight
    if (rem >= 2)      asm volatile("s_waitcnt vmcnt(8)" ::: "memory");
    else if (rem == 1) asm volatile("s_waitcnt vmcnt(4)" ::: "memory");
    else               asm volatile("s_waitcnt vmcnt(0)" ::: "memory");
    asm volatile("s_barrier" ::: "memory");

    unsigned aB = (unsigned)(unsigned long long)(void*)&As[cur][0];
    unsigned bB = (unsigned)(unsigned long long)(void*)&Bs[cur][0];

    // ---- phase A: stage A-half of t+3; read af[0-3]+bf[0-3]; 16 MFMA ----
    if (t + 3 < nkt) stageA(t + 3, (t + 3) & 3);
    s16x8 af[8], bfv[4];
    #pragma unroll
    for (int mf = 0; mf < 4; mf++) af[mf] = lds_read_b128(aB + aoffB[mf]);
    #pragma unroll
    for (int nf = 0; nf < 4; nf++) bfv[nf] = lds_read_b128(bB + boffB[nf]);
    asm volatile("s_waitcnt lgkmcnt(0)" ::: "memory");
    __builtin_amdgcn_sched_barrier(0);
    __builtin_amdgcn_s_setprio(1);
    #pragma unroll
    for (int mf = 0; mf < 4; mf++)
      #pragma unroll
      for (int nf = 0; nf < 4; nf++)
        acc[mf][nf] = __builtin_amdgcn_mfma_f32_16x16x32_bf16(af[mf], bfv[nf], acc[mf][nf], 0, 0, 0);
    __builtin_amdgcn_s_setprio(0);

    // ---- phase B: stage B-half of t+3; read af[4-7]; 16 MFMA ----
    if (t + 3 < nkt) stageB(t + 3, (t + 3) & 3);
    #pragma unroll
    for (int mf = 4; mf < 8; mf++) af[mf] = lds_read_b128(aB + aoffB[mf]);
    asm volatile("s_waitcnt lgkmcnt(0)" ::: "memory");
    __builtin_amdgcn_sched_barrier(0);
    __builtin_amdgcn_s_setprio(1);
    #pragma unroll
    for (int mf = 4; mf < 8; mf++)
      #pragma unroll
      for (int nf = 0; nf < 4; nf++)
        acc[mf][nf] = __builtin_amdgcn_mfma_f32_16x16x32_bf16(af[mf], bfv[nf], acc[mf][nf], 0, 0, 0);
    __builtin_amdgcn_s_setprio(0);
  }

  #pragma unroll
  for (int mf = 0; mf < 8; mf++)
    #pragma unroll
    for (int nf = 0; nf < 4; nf++)
      #pragma unroll
      for (int r = 0; r < 4; r++) {
        int row = m0 + wm + mf * 16 + q4 * 4 + r;
        int col = n0 + wn + nf * 16 + l16;
        float v = acc[mf][nf][r];
        if (OUTBF16) ((unsigned short*)outp)[(size_t)row * Nn + col] = f2bf(v);
        else         ((float*)outp)[(size_t)row * Nn + col] = v;
      }
}

// ---------------- RMSNorm + RoPE + scale ----------------
// NOTE: q scale folds in log2(e) so attention can use exp2 directly
// (softmax is exactly invariant: p = exp(S-m) = 2^(S*log2e - m*log2e)).
__global__ __launch_bounds__(256) void postproc(
    const unsigned short* __restrict__ qkv, unsigned short* __restrict__ qr,
    unsigned short* __restrict__ kr, const float* __restrict__ stab, const float* __restrict__ ctab) {
  __shared__ float sh[NHC + KHC];
  __shared__ float redq[4], redk[4];
  int row = blockIdx.x;
  int t = row & (TT - 1);
  int tid = threadIdx.x;
  const unsigned short* base = qkv + (size_t)row * QKVC;
  float sq = 0.f, sk = 0.f;
  uint4 qv = *(const uint4*)&base[tid * 8];
  const unsigned short* qp = (const unsigned short*)&qv;
  #pragma unroll
  for (int i = 0; i < 8; i++) { float f = bf2f(qp[i]); sh[tid*8 + i] = f; sq += f*f; }
  unsigned kv = *(const unsigned*)&base[NHC + tid*2];
  {
    float f0 = bf2f((unsigned short)(kv & 0xffff));
    float f1 = bf2f((unsigned short)(kv >> 16));
    sh[NHC + tid*2] = f0; sh[NHC + tid*2 + 1] = f1;
    sk += f0*f0 + f1*f1;
  }
  #pragma unroll
  for (int off = 32; off > 0; off >>= 1) { sq += __shfl_xor(sq, off); sk += __shfl_xor(sk, off); }
  if ((tid & 63) == 0) { redq[tid >> 6] = sq; redk[tid >> 6] = sk; }
  __syncthreads();
  float fq = rsqrtf((redq[0]+redq[1]+redq[2]+redq[3]) * (1.f/NHC) + 1e-6f)
             * (0.08838834764831845f * 1.4426950408889634f);
  float fk = rsqrtf((redk[0]+redk[1]+redk[2]+redk[3]) * (1.f/KHC) + 1e-6f);
  #pragma unroll
  for (int pi = 0; pi < 4; pi++) {
    int P = pi * 256 + tid;
    int head = P >> 6, i = P & 63;
    float s = stab[t*64 + i], c = ctab[t*64 + i];
    float x1 = sh[head*128 + i], x2 = sh[head*128 + i + 64];
    qr[(size_t)row * NHC + head*128 + i]      = f2bf((x1*c - x2*s) * fq);
    qr[(size_t)row * NHC + head*128 + i + 64] = f2bf((x2*c + x1*s) * fq);
  }
  {
    int head = tid >> 6, i = tid & 63;
    float s = stab[t*64 + i], c = ctab[t*64 + i];
    float x1 = sh[NHC + head*128 + i], x2 = sh[NHC + head*128 + i + 64];
    kr[(size_t)row * KHC + head*128 + i]      = f2bf((x1*c - x2*s) * fk);
    kr[(size_t)row * KHC + head*128 + i + 64] = f2bf((x2*c + x1*s) * fk);
  }
}

// ---------------- flash attention v4 (unchanged; 198-205us verified) ----------------
__global__ __launch_bounds__(256, 2) void attn(
    const unsigned short* __restrict__ qr, const unsigned short* __restrict__ kr,
    const unsigned short* __restrict__ vT, unsigned short* __restrict__ enc) {
  __shared__ unsigned short Ks[2][64 * 128];   // 16KB each; Ks[0]+Ks[1] holds Q in prologue
  __shared__ unsigned short Vs[2][128 * 64];   // 16KB each, layout [h][s-chunk]
  int tid = threadIdx.x;
  int wave = tid >> 6, lane = tid & 63, q4 = lane >> 4, l16 = lane & 15;
  int bid = blockIdx.x;
  int qt = bid & 15, n = (bid >> 4) & 15, b = bid >> 8, kh = n >> 2;

  const unsigned short* kbase = kr + ((size_t)(b * TT)) * KHC + kh * HD;
  const unsigned short* vbase = vT + ((size_t)((b * KVH + kh) * HD)) * TT;

  auto stageK = [&](int j, int kb) {
    const unsigned short* base = kbase + (size_t)(j * 64) * KHC;
    #pragma unroll
    for (int t = 0; t < 4; t++) {
      int L = wave * 4 + t;
      int r = L * 4 + (lane >> 4);
      int cg = (lane & 15) ^ (r & 7);
      glld16(base + (size_t)r * KHC + cg * 8, &Ks[kb][L * 512]);
    }
  };
  auto stageV = [&](int j, int vb) {
    const unsigned short* base = vbase + j * 64;
    #pragma unroll
    for (int t = 0; t < 4; t++) {
      int L = wave * 4 + t;
      int r = L * 8 + (lane >> 3);
      int cg = (lane & 7) ^ (r & 7);
      glld16(base + (size_t)r * TT + cg * 8, &Vs[vb][L * 512]);
    }
  };

  {
    const unsigned short* base = qr + ((size_t)(b * TT + qt * 128)) * NHC + n * HD;
    #pragma unroll
    for (int t = 0; t < 8; t++) {
      int L = wave * 8 + t;
      int r = L * 4 + (lane >> 4);
      int cg = (lane & 15) ^ (r & 7);
      glld16(base + (size_t)r * NHC + cg * 8, (unsigned short*)Ks + L * 512);
    }
  }
  stageV(0, 0);
  asm volatile("s_waitcnt vmcnt(0)" ::: "memory");
  __syncthreads();
  s16x8 qf[2][4];
  #pragma unroll
  for (int qb = 0; qb < 2; qb++)
    #pragma unroll
    for (int ku = 0; ku < 4; ku++) {
      int r = wave * 32 + qb * 16 + l16;
      qf[qb][ku] = *(const s16x8*)&((const unsigned short*)Ks)[r * 128 + (((ku * 4 + q4) ^ (r & 7)) << 3)];
    }
  __syncthreads();
  stageK(0, 0);
  asm volatile("s_waitcnt vmcnt(0)" ::: "memory");
  __syncthreads();

  float m_st[2] = {-1e30f, -1e30f}, l_st[2] = {0.f, 0.f};
  f32x4 O[2][8];
  #pragma unroll
  for (int qb = 0; qb < 2; qb++)
    #pragma unroll
    for (int hb = 0; hb < 8; hb++) O[qb][hb] = f32x4{0.f, 0.f, 0.f, 0.f};

  for (int j = 0; j < 32; j++) {
    int cur = j & 1;
    if (j < 31) { stageK(j + 1, cur ^ 1); stageV(j + 1, cur ^ 1); }
    f32x4 S[2][4];
    #pragma unroll
    for (int qb = 0; qb < 2; qb++)
      #pragma unroll
      for (int mb = 0; mb < 4; mb++) S[qb][mb] = f32x4{0.f, 0.f, 0.f, 0.f};
    __builtin_amdgcn_s_setprio(1);
    #pragma unroll
    for (int mb = 0; mb < 4; mb++) {
      int r = mb * 16 + l16;
      #pragma unroll
      for (int ku = 0; ku < 4; ku++) {
        s16x8 kf = *(const s16x8*)&Ks[cur][r * 128 + (((ku * 4 + q4) ^ (r & 7)) << 3)];
        S[0][mb] = __builtin_amdgcn_mfma_f32_16x16x32_bf16(kf, qf[0][ku], S[0][mb], 0, 0, 0);
        S[1][mb] = __builtin_amdgcn_mfma_f32_16x16x32_bf16(kf, qf[1][ku], S[1][mb], 0, 0, 0);
      }
    }
    __builtin_amdgcn_s_setprio(0);
    s16x8 pf8[2][2];
    #pragma unroll
    for (int qb = 0; qb < 2; qb++) {
      float mx = -1e30f;
      #pragma unroll
      for (int mb = 0; mb < 4; mb++)
        #pragma unroll
        for (int r = 0; r < 4; r++) mx = fmaxf(mx, S[qb][mb][r]);
      mx = fmaxf(mx, __shfl_xor(mx, 16));
      mx = fmaxf(mx, __shfl_xor(mx, 32));
      if (!__all(mx - m_st[qb] <= 8.f)) {
        float alpha = EXP2F(m_st[qb] - mx);
        m_st[qb] = mx;
        l_st[qb] *= alpha;
        #pragma unroll
        for (int hb = 0; hb < 8; hb++) O[qb][hb] *= alpha;
      }
      float mcur = m_st[qb];
      float rs = 0.f;
      #pragma unroll
      for (int mb = 0; mb < 4; mb++)
        #pragma unroll
        for (int r = 0; r < 4; r++) {
          float p = EXP2F(S[qb][mb][r] - mcur);
          rs += p;
          pf8[qb][mb >> 1][(mb & 1) * 4 + r] = (short)f2bf(p);
        }
      rs += __shfl_xor(rs, 16);
      rs += __shfl_xor(rs, 32);
      l_st[qb] += rs;
    }
    __builtin_amdgcn_s_setprio(1);
    #pragma unroll
    for (int su = 0; su < 2; su++) {
      #pragma unroll
      for (int hb = 0; hb < 8; hb++) {
        int r = hb * 16 + l16;
        int c0 = su * 8 + q4;
        int c1 = c0 + 4;
        s16x4 v0 = *(const s16x4*)&Vs[cur][r * 64 + (((c0 >> 1) ^ (r & 7)) << 3) + ((c0 & 1) << 2)];
        s16x4 v1 = *(const s16x4*)&Vs[cur][r * 64 + (((c1 >> 1) ^ (r & 7)) << 3) + ((c1 & 1) << 2)];
        s16x8 vf = __builtin_shufflevector(v0, v1, 0, 1, 2, 3, 4, 5, 6, 7);
        O[0][hb] = __builtin_amdgcn_mfma_f32_16x16x32_bf16(vf, pf8[0][su], O[0][hb], 0, 0, 0);
        O[1][hb] = __builtin_amdgcn_mfma_f32_16x16x32_bf16(vf, pf8[1][su], O[1][hb], 0, 0, 0);
      }
    }
    __builtin_amdgcn_s_setprio(0);
    asm volatile("s_waitcnt vmcnt(0)" ::: "memory");
    __syncthreads();
  }
  #pragma unroll
  for (int qb = 0; qb < 2; qb++) {
    float inv = 1.f / l_st[qb];
    int t = b * TT + qt * 128 + wave * 32 + qb * 16 + l16;
    #pragma unroll
    for (int hb = 0; hb < 8; hb++) {
      ushort4 o;
      o.x = f2bf(O[qb][hb][0] * inv);
      o.y = f2bf(O[qb][hb][1] * inv);
      o.z = f2bf(O[qb][hb][2] * inv);
      o.w = f2bf(O[qb][hb][3] * inv);
      *(ushort4*)&enc[(size_t)t * NHC + n * HD + hb * 16 + q4 * 4] = o;
    }
  }
}

extern "C" void kernel_launch(void* const* d_in, const int* in_sizes, int n_in,
                              void* d_out, int out_size, void* d_ws, size_t ws_size,
                              hipStream_t stream) {
  const float* x  = (const float*)d_in[0];
  const float* Wq = (const float*)d_in[1];
  const float* Wk = (const float*)d_in[2];
  const float* Wv = (const float*)d_in[3];
  const float* Wo = (const float*)d_in[4];
  float* out = (float*)d_out;

  char* ws = (char*)d_ws;
  size_t off = 0;
  auto alloc = [&](size_t bytes) -> void* {
    void* p = ws + off;
    off += (bytes + 255) & ~(size_t)255;
    return p;
  };
  unsigned short* xb    = (unsigned short*)alloc((size_t)BT * CC * 2);
  unsigned short* wqkvt = (unsigned short*)alloc((size_t)QKVC * CC * 2);
  unsigned short* wot   = (unsigned short*)alloc((size_t)CC * NHC * 2);
  unsigned short* qkv   = (unsigned short*)alloc((size_t)BT * QKVC * 2);
  unsigned short* qrb   = (unsigned short*)alloc((size_t)BT * NHC * 2);
  unsigned short* krb   = (unsigned short*)alloc((size_t)BT * KHC * 2);
  unsigned short* vTb   = (unsigned short*)alloc((size_t)BB * KVH * HD * TT * 2);
  unsigned short* encb  = (unsigned short*)alloc((size_t)BT * NHC * 2);
  float* stab = (float*)alloc((size_t)TT * 64 * 4);
  float* ctab = (float*)alloc((size_t)TT * 64 * 4);

  dim3 tb(32, 8);
  cvt_f2b<<<(BT*CC/4 + 255)/256, 256, 0, stream>>>(x, xb, BT*CC/4);
  trans_f2b<<<dim3(NHC/32, CC/32), tb, 0, stream>>>(Wq, wqkvt, CC, NHC);
  trans_f2b<<<dim3(KHC/32, CC/32), tb, 0, stream>>>(Wk, wqkvt + (size_t)NHC*CC, CC, KHC);
  trans_f2b<<<dim3(KHC/32, CC/32), tb, 0, stream>>>(Wv, wqkvt + (size_t)(NHC+KHC)*CC, CC, KHC);
  trans_f2b<<<dim3(NHC/32, NHC/32), tb, 0, stream>>>(Wo, wot, NHC, CC);
  sincos_init<<<(TT*64 + 255)/256, 256, 0, stream>>>(stab, ctab);
  gemm256<1><<<(BT/256) * (QKVC/256), 512, 0, stream>>>(xb, wqkvt, qkv, BT, QKVC, CC);
  postproc<<<BT, 256, 0, stream>>>(qkv, qrb, krb, stab, ctab);
  trans_v<<<dim3(TT/32, HD/32, BB*KVH), tb, 0, stream>>>(qkv, vTb);
  attn<<<BB * NHEAD * (TT/128), 256, 0, stream>>>(qrb, krb, vTb, encb);
  gemm256<0><<<(BT/256) * (CC/256), 512, 0, stream>>>(encb, wot, out, BT, CC, NHC);
}

// Round 6
// 530.211 us; speedup vs baseline: 1.0034x; 1.0034x over previous
//
#include <hip/hip_runtime.h>
#include <hip/hip_bf16.h>
#include <math.h>

typedef __attribute__((ext_vector_type(4))) float f32x4;
typedef __attribute__((ext_vector_type(8))) short s16x8;
typedef __attribute__((ext_vector_type(4))) short s16x4;

#define BB 4
#define TT 2048
#define CC 2048
#define NHEAD 16
#define KVH 4
#define HD 128
#define BT (BB*TT)      // 8192
#define NHC 2048        // N*H
#define KHC 512         // K*H
#define QKVC 3072

__device__ __forceinline__ float bf2f(unsigned short u) {
  union { unsigned u; float f; } v; v.u = ((unsigned)u) << 16; return v.f;
}
__device__ __forceinline__ unsigned short f2bf(float f) {
  union { float f; unsigned u; } v; v.f = f;
  unsigned r = v.u + 0x7fff + ((v.u >> 16) & 1);
  return (unsigned short)(r >> 16);
}

#if defined(__has_builtin)
#if __has_builtin(__builtin_amdgcn_exp2f)
#define EXP2F(x) __builtin_amdgcn_exp2f(x)
#endif
#endif
#ifndef EXP2F
#define EXP2F(x) exp2f(x)
#endif

// ---- async global->LDS 16B (lane i lands at ldsbase + i*16; ldsbase must be wave-uniform) ----
__device__ __forceinline__ void glld16(const void* gsrc, void* ldsbase) {
  __builtin_amdgcn_global_load_lds(
      (const __attribute__((address_space(1))) unsigned int*)gsrc,
      (__attribute__((address_space(3))) unsigned int*)(unsigned int)(unsigned long long)ldsbase,
      16, 0, 0);
}

// ---- opaque LDS b128 read (compiler cannot reorder/insert waits; we order manually) ----
__device__ __forceinline__ s16x8 lds_read_b128(unsigned addr) {
  s16x8 r;
  asm volatile("ds_read_b128 %0, %1" : "=v"(r) : "v"(addr));
  return r;
}

#define MFMA_BF16(a, b, c) __builtin_amdgcn_mfma_f32_16x16x32_bf16((a), (b), (c), 0, 0, 0)

// ---------------- fp32 -> bf16 elementwise ----------------
__global__ void cvt_f2b(const float* __restrict__ in, unsigned short* __restrict__ out, int n4) {
  int i = blockIdx.x * 256 + threadIdx.x;
  if (i >= n4) return;
  float4 v = ((const float4*)in)[i];
  ushort4 o;
  o.x = f2bf(v.x); o.y = f2bf(v.y); o.z = f2bf(v.z); o.w = f2bf(v.w);
  ((ushort4*)out)[i] = o;
}

// ---------------- fp32 [R][Cc] -> bf16 [Cc][R] transpose ----------------
__global__ void trans_f2b(const float* __restrict__ in, unsigned short* __restrict__ out, int R, int Cc) {
  __shared__ float tile[32][33];
  int c0 = blockIdx.x * 32, r0 = blockIdx.y * 32;
  int tx = threadIdx.x, ty = threadIdx.y;
  #pragma unroll
  for (int k = 0; k < 4; k++)
    tile[ty + 8*k][tx] = in[(size_t)(r0 + ty + 8*k) * Cc + c0 + tx];
  __syncthreads();
  #pragma unroll
  for (int k = 0; k < 4; k++)
    out[(size_t)(c0 + ty + 8*k) * R + r0 + tx] = f2bf(tile[tx][ty + 8*k]);
}

// ---------------- V slice transpose bf16 [s][h] -> [h][s] ----------------
__global__ void trans_v(const unsigned short* __restrict__ qkv, unsigned short* __restrict__ vT) {
  __shared__ unsigned short tile[32][33];
  int slice = blockIdx.z;           // b*4+kh
  int s0 = blockIdx.x * 32, h0 = blockIdx.y * 32;
  int tx = threadIdx.x, ty = threadIdx.y;
  const unsigned short* in = qkv + (size_t)(slice >> 2) * TT * QKVC + (NHC + KHC) + (slice & 3) * HD;
  unsigned short* out = vT + (size_t)slice * HD * TT;
  #pragma unroll
  for (int k = 0; k < 4; k++)
    tile[ty + 8*k][tx] = in[(size_t)(s0 + ty + 8*k) * QKVC + h0 + tx];
  __syncthreads();
  #pragma unroll
  for (int k = 0; k < 4; k++)
    out[(size_t)(h0 + ty + 8*k) * TT + s0 + tx] = tile[tx][ty + 8*k];
}

// ---------------- RoPE sin/cos table (fp64 precision) ----------------
__global__ void sincos_init(float* __restrict__ stab, float* __restrict__ ctab) {
  int idx = blockIdx.x * 256 + threadIdx.x;
  if (idx >= TT * 64) return;
  int t = idx >> 6, i = idx & 63;
  double inv = exp(-log(10000.0) * ((double)i / 64.0));
  double ang = (double)t * inv;
  stab[idx] = (float)sin(ang);
  ctab[idx] = (float)cos(ang);
}

// ---------------- NT GEMM 256x256, BK=64, 8 waves, 8-PHASE pipelined schedule ----------------
// Faithful port of the m194-m201 template (4 barrier-pair phases per K-tile):
//   phase = { asm ds_read subtile | stage 1 half-tile (2 glld16) |
//             s_barrier | lgkmcnt(0)+sched_barrier(0) | setprio+16 MFMA | s_barrier }
// Reads per tile (no LDS-read redundancy):
//   ph1: af[0-7][ks0] + bf[0-1][ks0]   ph2: af[0-7][ks1] + bf[2-3][ks0]
//   ph3: bf[0-1][ks1]                  ph4: bf[2-3][ks1]
// Stage stream (during tile kt): B(kt+1).h0, B(kt+1).h1, A(kt+2).h0, A(kt+2).h1.
//   - B targets buf[(kt+1)&1] (not being read this tile).
//   - A(kt+2) targets buf[kt&1].A, whose af reads all finish at ph2's lgkmcnt(0),
//     strictly before ph3's stage issues (ph2 end barrier separates all waves).
// Single counted vmcnt(4) at ph4 (A(kt+2)'s 4 loads stay in flight across the
// barrier; never drained to 0 in the main loop). Swizzle/fragment mapping and
// epilogue are byte-identical to the round-3-verified kernel.
template<int OUTBF16>
__global__ __launch_bounds__(512, 2) void gemm256(
    const unsigned short* __restrict__ A, const unsigned short* __restrict__ Bt,
    void* __restrict__ outp, int M, int Nn, int Kd) {
  __shared__ unsigned short As[2][256 * 64];   // 32 KiB per buf
  __shared__ unsigned short Bs[2][256 * 64];
  int tid = threadIdx.x;
  int wave = tid >> 6, lane = tid & 63, q4 = lane >> 4, l16 = lane & 15;

  int gx = Nn >> 8;
  int nwg = gridDim.x;
  int bid = blockIdx.x;
  int bid2 = (nwg & 7) ? bid : ((bid & 7) * (nwg >> 3) + (bid >> 3));
  int bx = bid2 % gx, by = bid2 / gx;
  int m0 = by * 256, n0 = bx * 256;
  int wm = (wave >> 2) * 128, wn = (wave & 3) * 64;

  f32x4 acc[8][4];
  #pragma unroll
  for (int i = 0; i < 8; i++)
    #pragma unroll
    for (int j = 0; j < 4; j++) acc[i][j] = f32x4{0.f, 0.f, 0.f, 0.f};

  // staging: half h of a tile = rows [h*128, h*128+128) x 64 K-shorts (16 KiB).
  // LDS 16B-chunk L = h*1024 + wave*128 + ld*64 + lane; row r = L>>3;
  // LDS slot s = L&7 holds global K-chunk cg = s ^ (r&7)  (pre-swizzled source).
  const unsigned short* Asrc[2][2];
  const unsigned short* Bsrc[2][2];
  #pragma unroll
  for (int h = 0; h < 2; h++)
    #pragma unroll
    for (int ld = 0; ld < 2; ld++) {
      int L = h * 1024 + wave * 128 + ld * 64 + lane;
      int r = L >> 3, cg = (L & 7) ^ (r & 7);
      Asrc[h][ld] = A + (size_t)(m0 + r) * Kd + cg * 8;
      Bsrc[h][ld] = Bt + (size_t)(n0 + r) * Kd + cg * 8;
    }
  auto stageA = [&](int kt, int h) {
    unsigned short* d = &As[kt & 1][(h * 1024 + wave * 128) * 8];
    glld16(Asrc[h][0] + (size_t)kt * 64, d);
    glld16(Asrc[h][1] + (size_t)kt * 64, d + 512);
  };
  auto stageB = [&](int kt, int h) {
    unsigned short* d = &Bs[kt & 1][(h * 1024 + wave * 128) * 8];
    glld16(Bsrc[h][0] + (size_t)kt * 64, d);
    glld16(Bsrc[h][1] + (size_t)kt * 64, d + 512);
  };

  // fragment read addressing: row R = wm/wn + f*16 + l16 (R&7 == l16&7);
  // global chunk c = ks*4+q4 lives at LDS slot c^(l16&7); byte = R*128 + slot*16
  unsigned asB = (unsigned)(unsigned long long)(void*)&As[0][0];
  unsigned bsB = (unsigned)(unsigned long long)(void*)&Bs[0][0];
  int aRow = (wm + l16) * 128;
  int bRow = (wn + l16) * 128;
  int slot0 = ((0 + q4) ^ (l16 & 7)) * 16;
  int slot1 = ((4 + q4) ^ (l16 & 7)) * 16;

  int nkt = Kd >> 6;     // 32 for both calls
  // prologue: tile0 (A+B) fully staged, then A(1); vmcnt(4) keeps A(1) in flight
  stageA(0, 0); stageA(0, 1); stageB(0, 0); stageB(0, 1);
  stageA(1, 0); stageA(1, 1);
  asm volatile("s_waitcnt vmcnt(4)" ::: "memory");
  asm volatile("s_barrier" ::: "memory");

  for (int kt = 0; kt < nkt; kt++) {
    unsigned aT = asB + (kt & 1) * 32768 + aRow;
    unsigned bT = bsB + (kt & 1) * 32768 + bRow;
    s16x8 af0[8], af1[8], bf0, bf1;

    // ---- phase 1: af[ks0] + bf[0-1][ks0] | stage B(kt+1).h0 | MFMA nf0-1 ks0 ----
    #pragma unroll
    for (int mf = 0; mf < 8; mf++) af0[mf] = lds_read_b128(aT + slot0 + mf * 2048);
    bf0 = lds_read_b128(bT + slot0);
    bf1 = lds_read_b128(bT + slot0 + 2048);
    if (kt + 1 < nkt) stageB(kt + 1, 0);
    asm volatile("s_barrier" ::: "memory");
    asm volatile("s_waitcnt lgkmcnt(0)" ::: "memory");
    __builtin_amdgcn_sched_barrier(0);
    __builtin_amdgcn_s_setprio(1);
    #pragma unroll
    for (int mf = 0; mf < 8; mf++) {
      acc[mf][0] = MFMA_BF16(af0[mf], bf0, acc[mf][0]);
      acc[mf][1] = MFMA_BF16(af0[mf], bf1, acc[mf][1]);
    }
    __builtin_amdgcn_s_setprio(0);
    asm volatile("s_barrier" ::: "memory");

    // ---- phase 2: af[ks1] + bf[2-3][ks0] | stage B(kt+1).h1 | MFMA nf2-3 ks0 ----
    #pragma unroll
    for (int mf = 0; mf < 8; mf++) af1[mf] = lds_read_b128(aT + slot1 + mf * 2048);
    bf0 = lds_read_b128(bT + slot0 + 2 * 2048);
    bf1 = lds_read_b128(bT + slot0 + 3 * 2048);
    if (kt + 1 < nkt) stageB(kt + 1, 1);
    asm volatile("s_barrier" ::: "memory");
    asm volatile("s_waitcnt lgkmcnt(0)" ::: "memory");
    __builtin_amdgcn_sched_barrier(0);
    __builtin_amdgcn_s_setprio(1);
    #pragma unroll
    for (int mf = 0; mf < 8; mf++) {
      acc[mf][2] = MFMA_BF16(af0[mf], bf0, acc[mf][2]);
      acc[mf][3] = MFMA_BF16(af0[mf], bf1, acc[mf][3]);
    }
    __builtin_amdgcn_s_setprio(0);
    asm volatile("s_barrier" ::: "memory");

    // ---- phase 3: bf[0-1][ks1] | stage A(kt+2).h0 | MFMA nf0-1 ks1 ----
    bf0 = lds_read_b128(bT + slot1);
    bf1 = lds_read_b128(bT + slot1 + 2048);
    if (kt + 2 < nkt) stageA(kt + 2, 0);
    asm volatile("s_barrier" ::: "memory");
    asm volatile("s_waitcnt lgkmcnt(0)" ::: "memory");
    __builtin_amdgcn_sched_barrier(0);
    __builtin_amdgcn_s_setprio(1);
    #pragma unroll
    for (int mf = 0; mf < 8; mf++) {
      acc[mf][0] = MFMA_BF16(af1[mf], bf0, acc[mf][0]);
      acc[mf][1] = MFMA_BF16(af1[mf], bf1, acc[mf][1]);
    }
    __builtin_amdgcn_s_setprio(0);
    asm volatile("s_barrier" ::: "memory");

    // ---- phase 4: bf[2-3][ks1] | stage A(kt+2).h1 | vmcnt(4) | MFMA nf2-3 ks1 ----
    bf0 = lds_read_b128(bT + slot1 + 2 * 2048);
    bf1 = lds_read_b128(bT + slot1 + 3 * 2048);
    if (kt + 2 < nkt) stageA(kt + 2, 1);
    if (kt < nkt - 2) asm volatile("s_waitcnt vmcnt(4)" ::: "memory");
    else              asm volatile("s_waitcnt vmcnt(0)" ::: "memory");
    asm volatile("s_barrier" ::: "memory");
    asm volatile("s_waitcnt lgkmcnt(0)" ::: "memory");
    __builtin_amdgcn_sched_barrier(0);
    __builtin_amdgcn_s_setprio(1);
    #pragma unroll
    for (int mf = 0; mf < 8; mf++) {
      acc[mf][2] = MFMA_BF16(af1[mf], bf0, acc[mf][2]);
      acc[mf][3] = MFMA_BF16(af1[mf], bf1, acc[mf][3]);
    }
    __builtin_amdgcn_s_setprio(0);
    asm volatile("s_barrier" ::: "memory");
  }

  #pragma unroll
  for (int mf = 0; mf < 8; mf++)
    #pragma unroll
    for (int nf = 0; nf < 4; nf++)
      #pragma unroll
      for (int r = 0; r < 4; r++) {
        int row = m0 + wm + mf * 16 + q4 * 4 + r;
        int col = n0 + wn + nf * 16 + l16;
        float v = acc[mf][nf][r];
        if (OUTBF16) ((unsigned short*)outp)[(size_t)row * Nn + col] = f2bf(v);
        else         ((float*)outp)[(size_t)row * Nn + col] = v;
      }
}

// ---------------- RMSNorm + RoPE + scale ----------------
// NOTE: q scale folds in log2(e) so attention can use exp2 directly
// (softmax is exactly invariant: p = exp(S-m) = 2^(S*log2e - m*log2e)).
__global__ __launch_bounds__(256) void postproc(
    const unsigned short* __restrict__ qkv, unsigned short* __restrict__ qr,
    unsigned short* __restrict__ kr, const float* __restrict__ stab, const float* __restrict__ ctab) {
  __shared__ float sh[NHC + KHC];
  __shared__ float redq[4], redk[4];
  int row = blockIdx.x;
  int t = row & (TT - 1);
  int tid = threadIdx.x;
  const unsigned short* base = qkv + (size_t)row * QKVC;
  float sq = 0.f, sk = 0.f;
  uint4 qv = *(const uint4*)&base[tid * 8];
  const unsigned short* qp = (const unsigned short*)&qv;
  #pragma unroll
  for (int i = 0; i < 8; i++) { float f = bf2f(qp[i]); sh[tid*8 + i] = f; sq += f*f; }
  unsigned kv = *(const unsigned*)&base[NHC + tid*2];
  {
    float f0 = bf2f((unsigned short)(kv & 0xffff));
    float f1 = bf2f((unsigned short)(kv >> 16));
    sh[NHC + tid*2] = f0; sh[NHC + tid*2 + 1] = f1;
    sk += f0*f0 + f1*f1;
  }
  #pragma unroll
  for (int off = 32; off > 0; off >>= 1) { sq += __shfl_xor(sq, off); sk += __shfl_xor(sk, off); }
  if ((tid & 63) == 0) { redq[tid >> 6] = sq; redk[tid >> 6] = sk; }
  __syncthreads();
  float fq = rsqrtf((redq[0]+redq[1]+redq[2]+redq[3]) * (1.f/NHC) + 1e-6f)
             * (0.08838834764831845f * 1.4426950408889634f);
  float fk = rsqrtf((redk[0]+redk[1]+redk[2]+redk[3]) * (1.f/KHC) + 1e-6f);
  #pragma unroll
  for (int pi = 0; pi < 4; pi++) {
    int P = pi * 256 + tid;
    int head = P >> 6, i = P & 63;
    float s = stab[t*64 + i], c = ctab[t*64 + i];
    float x1 = sh[head*128 + i], x2 = sh[head*128 + i + 64];
    qr[(size_t)row * NHC + head*128 + i]      = f2bf((x1*c - x2*s) * fq);
    qr[(size_t)row * NHC + head*128 + i + 64] = f2bf((x2*c + x1*s) * fq);
  }
  {
    int head = tid >> 6, i = tid & 63;
    float s = stab[t*64 + i], c = ctab[t*64 + i];
    float x1 = sh[NHC + head*128 + i], x2 = sh[NHC + head*128 + i + 64];
    kr[(size_t)row * KHC + head*128 + i]      = f2bf((x1*c - x2*s) * fk);
    kr[(size_t)row * KHC + head*128 + i + 64] = f2bf((x2*c + x1*s) * fk);
  }
}

// ---------------- flash attention v4 (unchanged; 198-205us verified) ----------------
__global__ __launch_bounds__(256, 2) void attn(
    const unsigned short* __restrict__ qr, const unsigned short* __restrict__ kr,
    const unsigned short* __restrict__ vT, unsigned short* __restrict__ enc) {
  __shared__ unsigned short Ks[2][64 * 128];   // 16KB each; Ks[0]+Ks[1] holds Q in prologue
  __shared__ unsigned short Vs[2][128 * 64];   // 16KB each, layout [h][s-chunk]
  int tid = threadIdx.x;
  int wave = tid >> 6, lane = tid & 63, q4 = lane >> 4, l16 = lane & 15;
  int bid = blockIdx.x;
  int qt = bid & 15, n = (bid >> 4) & 15, b = bid >> 8, kh = n >> 2;

  const unsigned short* kbase = kr + ((size_t)(b * TT)) * KHC + kh * HD;
  const unsigned short* vbase = vT + ((size_t)((b * KVH + kh) * HD)) * TT;

  auto stageK = [&](int j, int kb) {
    const unsigned short* base = kbase + (size_t)(j * 64) * KHC;
    #pragma unroll
    for (int t = 0; t < 4; t++) {
      int L = wave * 4 + t;
      int r = L * 4 + (lane >> 4);
      int cg = (lane & 15) ^ (r & 7);
      glld16(base + (size_t)r * KHC + cg * 8, &Ks[kb][L * 512]);
    }
  };
  auto stageV = [&](int j, int vb) {
    const unsigned short* base = vbase + j * 64;
    #pragma unroll
    for (int t = 0; t < 4; t++) {
      int L = wave * 4 + t;
      int r = L * 8 + (lane >> 3);
      int cg = (lane & 7) ^ (r & 7);
      glld16(base + (size_t)r * TT + cg * 8, &Vs[vb][L * 512]);
    }
  };

  {
    const unsigned short* base = qr + ((size_t)(b * TT + qt * 128)) * NHC + n * HD;
    #pragma unroll
    for (int t = 0; t < 8; t++) {
      int L = wave * 8 + t;
      int r = L * 4 + (lane >> 4);
      int cg = (lane & 15) ^ (r & 7);
      glld16(base + (size_t)r * NHC + cg * 8, (unsigned short*)Ks + L * 512);
    }
  }
  stageV(0, 0);
  asm volatile("s_waitcnt vmcnt(0)" ::: "memory");
  __syncthreads();
  s16x8 qf[2][4];
  #pragma unroll
  for (int qb = 0; qb < 2; qb++)
    #pragma unroll
    for (int ku = 0; ku < 4; ku++) {
      int r = wave * 32 + qb * 16 + l16;
      qf[qb][ku] = *(const s16x8*)&((const unsigned short*)Ks)[r * 128 + (((ku * 4 + q4) ^ (r & 7)) << 3)];
    }
  __syncthreads();
  stageK(0, 0);
  asm volatile("s_waitcnt vmcnt(0)" ::: "memory");
  __syncthreads();

  float m_st[2] = {-1e30f, -1e30f}, l_st[2] = {0.f, 0.f};
  f32x4 O[2][8];
  #pragma unroll
  for (int qb = 0; qb < 2; qb++)
    #pragma unroll
    for (int hb = 0; hb < 8; hb++) O[qb][hb] = f32x4{0.f, 0.f, 0.f, 0.f};

  for (int j = 0; j < 32; j++) {
    int cur = j & 1;
    if (j < 31) { stageK(j + 1, cur ^ 1); stageV(j + 1, cur ^ 1); }
    f32x4 S[2][4];
    #pragma unroll
    for (int qb = 0; qb < 2; qb++)
      #pragma unroll
      for (int mb = 0; mb < 4; mb++) S[qb][mb] = f32x4{0.f, 0.f, 0.f, 0.f};
    __builtin_amdgcn_s_setprio(1);
    #pragma unroll
    for (int mb = 0; mb < 4; mb++) {
      int r = mb * 16 + l16;
      #pragma unroll
      for (int ku = 0; ku < 4; ku++) {
        s16x8 kf = *(const s16x8*)&Ks[cur][r * 128 + (((ku * 4 + q4) ^ (r & 7)) << 3)];
        S[0][mb] = __builtin_amdgcn_mfma_f32_16x16x32_bf16(kf, qf[0][ku], S[0][mb], 0, 0, 0);
        S[1][mb] = __builtin_amdgcn_mfma_f32_16x16x32_bf16(kf, qf[1][ku], S[1][mb], 0, 0, 0);
      }
    }
    __builtin_amdgcn_s_setprio(0);
    s16x8 pf8[2][2];
    #pragma unroll
    for (int qb = 0; qb < 2; qb++) {
      float mx = -1e30f;
      #pragma unroll
      for (int mb = 0; mb < 4; mb++)
        #pragma unroll
        for (int r = 0; r < 4; r++) mx = fmaxf(mx, S[qb][mb][r]);
      mx = fmaxf(mx, __shfl_xor(mx, 16));
      mx = fmaxf(mx, __shfl_xor(mx, 32));
      if (!__all(mx - m_st[qb] <= 8.f)) {
        float alpha = EXP2F(m_st[qb] - mx);
        m_st[qb] = mx;
        l_st[qb] *= alpha;
        #pragma unroll
        for (int hb = 0; hb < 8; hb++) O[qb][hb] *= alpha;
      }
      float mcur = m_st[qb];
      float rs = 0.f;
      #pragma unroll
      for (int mb = 0; mb < 4; mb++)
        #pragma unroll
        for (int r = 0; r < 4; r++) {
          float p = EXP2F(S[qb][mb][r] - mcur);
          rs += p;
          pf8[qb][mb >> 1][(mb & 1) * 4 + r] = (short)f2bf(p);
        }
      rs += __shfl_xor(rs, 16);
      rs += __shfl_xor(rs, 32);
      l_st[qb] += rs;
    }
    __builtin_amdgcn_s_setprio(1);
    #pragma unroll
    for (int su = 0; su < 2; su++) {
      #pragma unroll
      for (int hb = 0; hb < 8; hb++) {
        int r = hb * 16 + l16;
        int c0 = su * 8 + q4;
        int c1 = c0 + 4;
        s16x4 v0 = *(const s16x4*)&Vs[cur][r * 64 + (((c0 >> 1) ^ (r & 7)) << 3) + ((c0 & 1) << 2)];
        s16x4 v1 = *(const s16x4*)&Vs[cur][r * 64 + (((c1 >> 1) ^ (r & 7)) << 3) + ((c1 & 1) << 2)];
        s16x8 vf = __builtin_shufflevector(v0, v1, 0, 1, 2, 3, 4, 5, 6, 7);
        O[0][hb] = __builtin_amdgcn_mfma_f32_16x16x32_bf16(vf, pf8[0][su], O[0][hb], 0, 0, 0);
        O[1][hb] = __builtin_amdgcn_mfma_f32_16x16x32_bf16(vf, pf8[1][su], O[1][hb], 0, 0, 0);
      }
    }
    __builtin_amdgcn_s_setprio(0);
    asm volatile("s_waitcnt vmcnt(0)" ::: "memory");
    __syncthreads();
  }
  #pragma unroll
  for (int qb = 0; qb < 2; qb++) {
    float inv = 1.f / l_st[qb];
    int t = b * TT + qt * 128 + wave * 32 + qb * 16 + l16;
    #pragma unroll
    for (int hb = 0; hb < 8; hb++) {
      ushort4 o;
      o.x = f2bf(O[qb][hb][0] * inv);
      o.y = f2bf(O[qb][hb][1] * inv);
      o.z = f2bf(O[qb][hb][2] * inv);
      o.w = f2bf(O[qb][hb][3] * inv);
      *(ushort4*)&enc[(size_t)t * NHC + n * HD + hb * 16 + q4 * 4] = o;
    }
  }
}

extern "C" void kernel_launch(void* const* d_in, const int* in_sizes, int n_in,
                              void* d_out, int out_size, void* d_ws, size_t ws_size,
                              hipStream_t stream) {
  const float* x  = (const float*)d_in[0];
  const float* Wq = (const float*)d_in[1];
  const float* Wk = (const float*)d_in[2];
  const float* Wv = (const float*)d_in[3];
  const float* Wo = (const float*)d_in[4];
  float* out = (float*)d_out;

  char* ws = (char*)d_ws;
  size_t off = 0;
  auto alloc = [&](size_t bytes) -> void* {
    void* p = ws + off;
    off += (bytes + 255) & ~(size_t)255;
    return p;
  };
  unsigned short* xb    = (unsigned short*)alloc((size_t)BT * CC * 2);
  unsigned short* wqkvt = (unsigned short*)alloc((size_t)QKVC * CC * 2);
  unsigned short* wot   = (unsigned short*)alloc((size_t)CC * NHC * 2);
  unsigned short* qkv   = (unsigned short*)alloc((size_t)BT * QKVC * 2);
  unsigned short* qrb   = (unsigned short*)alloc((size_t)BT * NHC * 2);
  unsigned short* krb   = (unsigned short*)alloc((size_t)BT * KHC * 2);
  unsigned short* vTb   = (unsigned short*)alloc((size_t)BB * KVH * HD * TT * 2);
  unsigned short* encb  = (unsigned short*)alloc((size_t)BT * NHC * 2);
  float* stab = (float*)alloc((size_t)TT * 64 * 4);
  float* ctab = (float*)alloc((size_t)TT * 64 * 4);

  dim3 tb(32, 8);
  cvt_f2b<<<(BT*CC/4 + 255)/256, 256, 0, stream>>>(x, xb, BT*CC/4);
  trans_f2b<<<dim3(NHC/32, CC/32), tb, 0, stream>>>(Wq, wqkvt, CC, NHC);
  trans_f2b<<<dim3(KHC/32, CC/32), tb, 0, stream>>>(Wk, wqkvt + (size_t)NHC*CC, CC, KHC);
  trans_f2b<<<dim3(KHC/32, CC/32), tb, 0, stream>>>(Wv, wqkvt + (size_t)(NHC+KHC)*CC, CC, KHC);
  trans_f2b<<<dim3(NHC/32, NHC/32), tb, 0, stream>>>(Wo, wot, NHC, CC);
  sincos_init<<<(TT*64 + 255)/256, 256, 0, stream>>>(stab, ctab);
  gemm256<1><<<(BT/256) * (QKVC/256), 512, 0, stream>>>(xb, wqkvt, qkv, BT, QKVC, CC);
  postproc<<<BT, 256, 0, stream>>>(qkv, qrb, krb, stab, ctab);
  trans_v<<<dim3(TT/32, HD/32, BB*KVH), tb, 0, stream>>>(qkv, vTb);
  attn<<<BB * NHEAD * (TT/128), 256, 0, stream>>>(qrb, krb, vTb, encb);
  gemm256<0><<<(BT/256) * (CC/256), 512, 0, stream>>>(encb, wot, out, BT, CC, NHC);
}

// Round 7
// 520.703 us; speedup vs baseline: 1.0217x; 1.0183x over previous
//
#include <hip/hip_runtime.h>
#include <hip/hip_bf16.h>
#include <math.h>

typedef __attribute__((ext_vector_type(4))) float f32x4;
typedef __attribute__((ext_vector_type(16))) float f32x16;
typedef __attribute__((ext_vector_type(8))) short s16x8;
typedef __attribute__((ext_vector_type(4))) short s16x4;

#define BB 4
#define TT 2048
#define CC 2048
#define NHEAD 16
#define KVH 4
#define HD 128
#define BT (BB*TT)      // 8192
#define NHC 2048        // N*H
#define KHC 512         // K*H
#define QKVC 3072

__device__ __forceinline__ float bf2f(unsigned short u) {
  union { unsigned u; float f; } v; v.u = ((unsigned)u) << 16; return v.f;
}
__device__ __forceinline__ unsigned short f2bf(float f) {
  union { float f; unsigned u; } v; v.f = f;
  unsigned r = v.u + 0x7fff + ((v.u >> 16) & 1);
  return (unsigned short)(r >> 16);
}
// HW packed f32->bf16 (RTNE), src0 -> low half, src1 -> high half (T12 recipe)
__device__ __forceinline__ unsigned cvt_pk_bf16(float lo, float hi) {
  unsigned r;
  asm("v_cvt_pk_bf16_f32 %0, %1, %2" : "=v"(r) : "v"(lo), "v"(hi));
  return r;
}

#if defined(__has_builtin)
#if __has_builtin(__builtin_amdgcn_exp2f)
#define EXP2F(x) __builtin_amdgcn_exp2f(x)
#endif
#endif
#ifndef EXP2F
#define EXP2F(x) exp2f(x)
#endif

// ---- async global->LDS 16B (lane i lands at ldsbase + i*16; ldsbase must be wave-uniform) ----
__device__ __forceinline__ void glld16(const void* gsrc, void* ldsbase) {
  __builtin_amdgcn_global_load_lds(
      (const __attribute__((address_space(1))) unsigned int*)gsrc,
      (__attribute__((address_space(3))) unsigned int*)(unsigned int)(unsigned long long)ldsbase,
      16, 0, 0);
}

// ---------------- fp32 -> bf16 elementwise ----------------
__global__ void cvt_f2b(const float* __restrict__ in, unsigned short* __restrict__ out, int n4) {
  int i = blockIdx.x * 256 + threadIdx.x;
  if (i >= n4) return;
  float4 v = ((const float4*)in)[i];
  ushort4 o;
  o.x = f2bf(v.x); o.y = f2bf(v.y); o.z = f2bf(v.z); o.w = f2bf(v.w);
  ((ushort4*)out)[i] = o;
}

// ---------------- fp32 [R][Cc] -> bf16 [Cc][R] transpose ----------------
__global__ void trans_f2b(const float* __restrict__ in, unsigned short* __restrict__ out, int R, int Cc) {
  __shared__ float tile[32][33];
  int c0 = blockIdx.x * 32, r0 = blockIdx.y * 32;
  int tx = threadIdx.x, ty = threadIdx.y;
  #pragma unroll
  for (int k = 0; k < 4; k++)
    tile[ty + 8*k][tx] = in[(size_t)(r0 + ty + 8*k) * Cc + c0 + tx];
  __syncthreads();
  #pragma unroll
  for (int k = 0; k < 4; k++)
    out[(size_t)(c0 + ty + 8*k) * R + r0 + tx] = f2bf(tile[tx][ty + 8*k]);
}

// ---------------- V slice transpose bf16 [s][h] -> [h][s] ----------------
__global__ void trans_v(const unsigned short* __restrict__ qkv, unsigned short* __restrict__ vT) {
  __shared__ unsigned short tile[32][33];
  int slice = blockIdx.z;           // b*4+kh
  int s0 = blockIdx.x * 32, h0 = blockIdx.y * 32;
  int tx = threadIdx.x, ty = threadIdx.y;
  const unsigned short* in = qkv + (size_t)(slice >> 2) * TT * QKVC + (NHC + KHC) + (slice & 3) * HD;
  unsigned short* out = vT + (size_t)slice * HD * TT;
  #pragma unroll
  for (int k = 0; k < 4; k++)
    tile[ty + 8*k][tx] = in[(size_t)(s0 + ty + 8*k) * QKVC + h0 + tx];
  __syncthreads();
  #pragma unroll
  for (int k = 0; k < 4; k++)
    out[(size_t)(h0 + ty + 8*k) * TT + s0 + tx] = tile[tx][ty + 8*k];
}

// ---------------- RoPE sin/cos table (fp64 precision) ----------------
__global__ void sincos_init(float* __restrict__ stab, float* __restrict__ ctab) {
  int idx = blockIdx.x * 256 + threadIdx.x;
  if (idx >= TT * 64) return;
  int t = idx >> 6, i = idx & 63;
  double inv = exp(-log(10000.0) * ((double)i / 64.0));
  double ang = (double)t * inv;
  stab[idx] = (float)sin(ang);
  ctab[idx] = (float)cos(ang);
}

// ---------------- NT GEMM 256x256, BK=64, 8 waves, 32x32x16 MFMA ----------------
// Round-7: schedule reverted to the round-3 2-phase (simplest of three
// equal-performing variants r3/r4/r6); MFMA switched to 32x32x16 bf16:
// half the MFMA instructions (32 vs 64 per K-tile/wave), ~15% higher
// matrix-pipe FLOP/cyc (m119: 2495 vs 2176 TF), same LDS read count.
// Staging geometry + swizzle byte-identical to verified r3. Fragment map:
//   A frag(mf,ks): row R = wm+mf*32+(lane&31), k-chunk c = ks*2+(lane>>5)
//   C/D: col = lane&31, row = (reg&3)+8*(reg>>2)+4*(lane>>5)  [m74/m101]
template<int OUTBF16>
__global__ __launch_bounds__(512, 2) void gemm256(
    const unsigned short* __restrict__ A, const unsigned short* __restrict__ Bt,
    void* __restrict__ outp, int M, int Nn, int Kd) {
  __shared__ unsigned short As[2][256 * 64];   // 32 KiB per buf
  __shared__ unsigned short Bs[2][256 * 64];
  int tid = threadIdx.x;
  int wave = tid >> 6, lane = tid & 63;
  int l32 = lane & 31, khf = lane >> 5;

  int gx = Nn >> 8;
  int nwg = gridDim.x;
  int bid = blockIdx.x;
  int bid2 = (nwg & 7) ? bid : ((bid & 7) * (nwg >> 3) + (bid >> 3));
  int bx = bid2 % gx, by = bid2 / gx;
  int m0 = by * 256, n0 = bx * 256;
  int wm = (wave >> 2) * 128, wn = (wave & 3) * 64;   // wave tile 128M x 64N

  f32x16 acc[4][2];
  #pragma unroll
  for (int i = 0; i < 4; i++)
    #pragma unroll
    for (int j = 0; j < 2; j++)
      #pragma unroll
      for (int r = 0; r < 16; r++) acc[i][j][r] = 0.f;

  const unsigned short* Abase = A + (size_t)m0 * Kd;
  const unsigned short* Bbase = Bt + (size_t)n0 * Kd;

  // staging (verified r3): chunk cf = (wave*4+t)*64+lane; r=cf>>3;
  // LDS slot s=cf&7 holds global chunk cg = s^(r&7) (pre-swizzled source)
  auto stage = [&](const unsigned short* Ak, const unsigned short* Bk, int buf) {
    #pragma unroll
    for (int t = 0; t < 4; t++) {
      int cf = (wave * 4 + t) * 64 + lane;
      int r = cf >> 3, cg = (cf & 7) ^ (r & 7);
      glld16(Ak + (size_t)r * Kd + cg * 8, &As[buf][(wave * 4 + t) * 512]);
    }
    #pragma unroll
    for (int t = 0; t < 4; t++) {
      int cf = (wave * 4 + t) * 64 + lane;
      int r = cf >> 3, cg = (cf & 7) ^ (r & 7);
      glld16(Bk + (size_t)r * Kd + cg * 8, &Bs[buf][(wave * 4 + t) * 512]);
    }
  };

  stage(Abase, Bbase, 0);
  __syncthreads();

  int nkt = Kd >> 6;
  for (int kt = 0; kt < nkt; kt++) {
    int cur = kt & 1;
    if (kt + 1 < nkt) stage(Abase + (kt + 1) * 64, Bbase + (kt + 1) * 64, cur ^ 1);
    #pragma unroll
    for (int ks = 0; ks < 4; ks++) {
      int c = ks * 2 + khf;                  // 16B k-chunk for this MFMA step
      s16x8 af[4], bfv[2];
      #pragma unroll
      for (int mf = 0; mf < 4; mf++) {
        int R = wm + mf * 32 + l32;
        af[mf] = *(const s16x8*)&As[cur][R * 64 + ((c ^ (R & 7)) << 3)];
      }
      #pragma unroll
      for (int nf = 0; nf < 2; nf++) {
        int R = wn + nf * 32 + l32;
        bfv[nf] = *(const s16x8*)&Bs[cur][R * 64 + ((c ^ (R & 7)) << 3)];
      }
      __builtin_amdgcn_s_setprio(1);
      #pragma unroll
      for (int mf = 0; mf < 4; mf++)
        #pragma unroll
        for (int nf = 0; nf < 2; nf++)
          acc[mf][nf] = __builtin_amdgcn_mfma_f32_32x32x16_bf16(af[mf], bfv[nf], acc[mf][nf], 0, 0, 0);
      __builtin_amdgcn_s_setprio(0);
    }
    __syncthreads();   // implicit vmcnt(0)+lgkmcnt(0): prefetch landed, reads done
  }

  #pragma unroll
  for (int mf = 0; mf < 4; mf++)
    #pragma unroll
    for (int nf = 0; nf < 2; nf++)
      #pragma unroll
      for (int r = 0; r < 16; r++) {
        int row = m0 + wm + mf * 32 + (r & 3) + 8 * (r >> 2) + 4 * khf;
        int col = n0 + wn + nf * 32 + l32;
        float v = acc[mf][nf][r];
        if (OUTBF16) ((unsigned short*)outp)[(size_t)row * Nn + col] = f2bf(v);
        else         ((float*)outp)[(size_t)row * Nn + col] = v;
      }
}

// ---------------- RMSNorm + RoPE + scale ----------------
// NOTE: q scale folds in log2(e) so attention can use exp2 directly
// (softmax is exactly invariant: p = exp(S-m) = 2^(S*log2e - m*log2e)).
__global__ __launch_bounds__(256) void postproc(
    const unsigned short* __restrict__ qkv, unsigned short* __restrict__ qr,
    unsigned short* __restrict__ kr, const float* __restrict__ stab, const float* __restrict__ ctab) {
  __shared__ float sh[NHC + KHC];
  __shared__ float redq[4], redk[4];
  int row = blockIdx.x;
  int t = row & (TT - 1);
  int tid = threadIdx.x;
  const unsigned short* base = qkv + (size_t)row * QKVC;
  float sq = 0.f, sk = 0.f;
  uint4 qv = *(const uint4*)&base[tid * 8];
  const unsigned short* qp = (const unsigned short*)&qv;
  #pragma unroll
  for (int i = 0; i < 8; i++) { float f = bf2f(qp[i]); sh[tid*8 + i] = f; sq += f*f; }
  unsigned kv = *(const unsigned*)&base[NHC + tid*2];
  {
    float f0 = bf2f((unsigned short)(kv & 0xffff));
    float f1 = bf2f((unsigned short)(kv >> 16));
    sh[NHC + tid*2] = f0; sh[NHC + tid*2 + 1] = f1;
    sk += f0*f0 + f1*f1;
  }
  #pragma unroll
  for (int off = 32; off > 0; off >>= 1) { sq += __shfl_xor(sq, off); sk += __shfl_xor(sk, off); }
  if ((tid & 63) == 0) { redq[tid >> 6] = sq; redk[tid >> 6] = sk; }
  __syncthreads();
  float fq = rsqrtf((redq[0]+redq[1]+redq[2]+redq[3]) * (1.f/NHC) + 1e-6f)
             * (0.08838834764831845f * 1.4426950408889634f);
  float fk = rsqrtf((redk[0]+redk[1]+redk[2]+redk[3]) * (1.f/KHC) + 1e-6f);
  #pragma unroll
  for (int pi = 0; pi < 4; pi++) {
    int P = pi * 256 + tid;
    int head = P >> 6, i = P & 63;
    float s = stab[t*64 + i], c = ctab[t*64 + i];
    float x1 = sh[head*128 + i], x2 = sh[head*128 + i + 64];
    qr[(size_t)row * NHC + head*128 + i]      = f2bf((x1*c - x2*s) * fq);
    qr[(size_t)row * NHC + head*128 + i + 64] = f2bf((x2*c + x1*s) * fq);
  }
  {
    int head = tid >> 6, i = tid & 63;
    float s = stab[t*64 + i], c = ctab[t*64 + i];
    float x1 = sh[NHC + head*128 + i], x2 = sh[NHC + head*128 + i + 64];
    kr[(size_t)row * KHC + head*128 + i]      = f2bf((x1*c - x2*s) * fk);
    kr[(size_t)row * KHC + head*128 + i + 64] = f2bf((x2*c + x1*s) * fk);
  }
}

// ---------------- flash attention v5: v4 + cvt_pk_bf16 P/O conversion ----------------
// Round-7 change (only): the 32 manual f2bf per iter (5 VALU ops each) in the
// softmax P-path are replaced by 16 v_cvt_pk_bf16_f32 (1 op per 2 values);
// same for the output epilogue. Everything else byte-identical to v4.
__global__ __launch_bounds__(256, 2) void attn(
    const unsigned short* __restrict__ qr, const unsigned short* __restrict__ kr,
    const unsigned short* __restrict__ vT, unsigned short* __restrict__ enc) {
  __shared__ unsigned short Ks[2][64 * 128];   // 16KB each; Ks[0]+Ks[1] holds Q in prologue
  __shared__ unsigned short Vs[2][128 * 64];   // 16KB each, layout [h][s-chunk]
  int tid = threadIdx.x;
  int wave = tid >> 6, lane = tid & 63, q4 = lane >> 4, l16 = lane & 15;
  int bid = blockIdx.x;
  int qt = bid & 15, n = (bid >> 4) & 15, b = bid >> 8, kh = n >> 2;

  const unsigned short* kbase = kr + ((size_t)(b * TT)) * KHC + kh * HD;
  const unsigned short* vbase = vT + ((size_t)((b * KVH + kh) * HD)) * TT;

  auto stageK = [&](int j, int kb) {
    const unsigned short* base = kbase + (size_t)(j * 64) * KHC;
    #pragma unroll
    for (int t = 0; t < 4; t++) {
      int L = wave * 4 + t;
      int r = L * 4 + (lane >> 4);
      int cg = (lane & 15) ^ (r & 7);
      glld16(base + (size_t)r * KHC + cg * 8, &Ks[kb][L * 512]);
    }
  };
  auto stageV = [&](int j, int vb) {
    const unsigned short* base = vbase + j * 64;
    #pragma unroll
    for (int t = 0; t < 4; t++) {
      int L = wave * 4 + t;
      int r = L * 8 + (lane >> 3);
      int cg = (lane & 7) ^ (r & 7);
      glld16(base + (size_t)r * TT + cg * 8, &Vs[vb][L * 512]);
    }
  };

  {
    const unsigned short* base = qr + ((size_t)(b * TT + qt * 128)) * NHC + n * HD;
    #pragma unroll
    for (int t = 0; t < 8; t++) {
      int L = wave * 8 + t;
      int r = L * 4 + (lane >> 4);
      int cg = (lane & 15) ^ (r & 7);
      glld16(base + (size_t)r * NHC + cg * 8, (unsigned short*)Ks + L * 512);
    }
  }
  stageV(0, 0);
  asm volatile("s_waitcnt vmcnt(0)" ::: "memory");
  __syncthreads();
  s16x8 qf[2][4];
  #pragma unroll
  for (int qb = 0; qb < 2; qb++)
    #pragma unroll
    for (int ku = 0; ku < 4; ku++) {
      int r = wave * 32 + qb * 16 + l16;
      qf[qb][ku] = *(const s16x8*)&((const unsigned short*)Ks)[r * 128 + (((ku * 4 + q4) ^ (r & 7)) << 3)];
    }
  __syncthreads();
  stageK(0, 0);
  asm volatile("s_waitcnt vmcnt(0)" ::: "memory");
  __syncthreads();

  float m_st[2] = {-1e30f, -1e30f}, l_st[2] = {0.f, 0.f};
  f32x4 O[2][8];
  #pragma unroll
  for (int qb = 0; qb < 2; qb++)
    #pragma unroll
    for (int hb = 0; hb < 8; hb++) O[qb][hb] = f32x4{0.f, 0.f, 0.f, 0.f};

  for (int j = 0; j < 32; j++) {
    int cur = j & 1;
    if (j < 31) { stageK(j + 1, cur ^ 1); stageV(j + 1, cur ^ 1); }
    f32x4 S[2][4];
    #pragma unroll
    for (int qb = 0; qb < 2; qb++)
      #pragma unroll
      for (int mb = 0; mb < 4; mb++) S[qb][mb] = f32x4{0.f, 0.f, 0.f, 0.f};
    __builtin_amdgcn_s_setprio(1);
    #pragma unroll
    for (int mb = 0; mb < 4; mb++) {
      int r = mb * 16 + l16;
      #pragma unroll
      for (int ku = 0; ku < 4; ku++) {
        s16x8 kf = *(const s16x8*)&Ks[cur][r * 128 + (((ku * 4 + q4) ^ (r & 7)) << 3)];
        S[0][mb] = __builtin_amdgcn_mfma_f32_16x16x32_bf16(kf, qf[0][ku], S[0][mb], 0, 0, 0);
        S[1][mb] = __builtin_amdgcn_mfma_f32_16x16x32_bf16(kf, qf[1][ku], S[1][mb], 0, 0, 0);
      }
    }
    __builtin_amdgcn_s_setprio(0);
    s16x8 pf8[2][2];
    #pragma unroll
    for (int qb = 0; qb < 2; qb++) {
      float mx = -1e30f;
      #pragma unroll
      for (int mb = 0; mb < 4; mb++)
        #pragma unroll
        for (int r = 0; r < 4; r++) mx = fmaxf(mx, S[qb][mb][r]);
      mx = fmaxf(mx, __shfl_xor(mx, 16));
      mx = fmaxf(mx, __shfl_xor(mx, 32));
      if (!__all(mx - m_st[qb] <= 8.f)) {
        float alpha = EXP2F(m_st[qb] - mx);
        m_st[qb] = mx;
        l_st[qb] *= alpha;
        #pragma unroll
        for (int hb = 0; hb < 8; hb++) O[qb][hb] *= alpha;
      }
      float mcur = m_st[qb];
      float rs = 0.f;
      #pragma unroll
      for (int su = 0; su < 2; su++) {
        union { s16x8 v; unsigned d[4]; } pu;
        #pragma unroll
        for (int hf = 0; hf < 2; hf++) {
          int mb = su * 2 + hf;
          float p0 = EXP2F(S[qb][mb][0] - mcur);
          float p1 = EXP2F(S[qb][mb][1] - mcur);
          float p2 = EXP2F(S[qb][mb][2] - mcur);
          float p3 = EXP2F(S[qb][mb][3] - mcur);
          rs += (p0 + p1) + (p2 + p3);
          pu.d[hf * 2 + 0] = cvt_pk_bf16(p0, p1);
          pu.d[hf * 2 + 1] = cvt_pk_bf16(p2, p3);
        }
        pf8[qb][su] = pu.v;
      }
      rs += __shfl_xor(rs, 16);
      rs += __shfl_xor(rs, 32);
      l_st[qb] += rs;
    }
    __builtin_amdgcn_s_setprio(1);
    #pragma unroll
    for (int su = 0; su < 2; su++) {
      #pragma unroll
      for (int hb = 0; hb < 8; hb++) {
        int r = hb * 16 + l16;
        int c0 = su * 8 + q4;
        int c1 = c0 + 4;
        s16x4 v0 = *(const s16x4*)&Vs[cur][r * 64 + (((c0 >> 1) ^ (r & 7)) << 3) + ((c0 & 1) << 2)];
        s16x4 v1 = *(const s16x4*)&Vs[cur][r * 64 + (((c1 >> 1) ^ (r & 7)) << 3) + ((c1 & 1) << 2)];
        s16x8 vf = __builtin_shufflevector(v0, v1, 0, 1, 2, 3, 4, 5, 6, 7);
        O[0][hb] = __builtin_amdgcn_mfma_f32_16x16x32_bf16(vf, pf8[0][su], O[0][hb], 0, 0, 0);
        O[1][hb] = __builtin_amdgcn_mfma_f32_16x16x32_bf16(vf, pf8[1][su], O[1][hb], 0, 0, 0);
      }
    }
    __builtin_amdgcn_s_setprio(0);
    asm volatile("s_waitcnt vmcnt(0)" ::: "memory");
    __syncthreads();
  }
  #pragma unroll
  for (int qb = 0; qb < 2; qb++) {
    float inv = 1.f / l_st[qb];
    int t = b * TT + qt * 128 + wave * 32 + qb * 16 + l16;
    #pragma unroll
    for (int hb = 0; hb < 8; hb++) {
      union { ushort4 s; unsigned d[2]; } o;
      o.d[0] = cvt_pk_bf16(O[qb][hb][0] * inv, O[qb][hb][1] * inv);
      o.d[1] = cvt_pk_bf16(O[qb][hb][2] * inv, O[qb][hb][3] * inv);
      *(ushort4*)&enc[(size_t)t * NHC + n * HD + hb * 16 + q4 * 4] = o.s;
    }
  }
}

extern "C" void kernel_launch(void* const* d_in, const int* in_sizes, int n_in,
                              void* d_out, int out_size, void* d_ws, size_t ws_size,
                              hipStream_t stream) {
  const float* x  = (const float*)d_in[0];
  const float* Wq = (const float*)d_in[1];
  const float* Wk = (const float*)d_in[2];
  const float* Wv = (const float*)d_in[3];
  const float* Wo = (const float*)d_in[4];
  float* out = (float*)d_out;

  char* ws = (char*)d_ws;
  size_t off = 0;
  auto alloc = [&](size_t bytes) -> void* {
    void* p = ws + off;
    off += (bytes + 255) & ~(size_t)255;
    return p;
  };
  unsigned short* xb    = (unsigned short*)alloc((size_t)BT * CC * 2);
  unsigned short* wqkvt = (unsigned short*)alloc((size_t)QKVC * CC * 2);
  unsigned short* wot   = (unsigned short*)alloc((size_t)CC * NHC * 2);
  unsigned short* qkv   = (unsigned short*)alloc((size_t)BT * QKVC * 2);
  unsigned short* qrb   = (unsigned short*)alloc((size_t)BT * NHC * 2);
  unsigned short* krb   = (unsigned short*)alloc((size_t)BT * KHC * 2);
  unsigned short* vTb   = (unsigned short*)alloc((size_t)BB * KVH * HD * TT * 2);
  unsigned short* encb  = (unsigned short*)alloc((size_t)BT * NHC * 2);
  float* stab = (float*)alloc((size_t)TT * 64 * 4);
  float* ctab = (float*)alloc((size_t)TT * 64 * 4);

  dim3 tb(32, 8);
  cvt_f2b<<<(BT*CC/4 + 255)/256, 256, 0, stream>>>(x, xb, BT*CC/4);
  trans_f2b<<<dim3(NHC/32, CC/32), tb, 0, stream>>>(Wq, wqkvt, CC, NHC);
  trans_f2b<<<dim3(KHC/32, CC/32), tb, 0, stream>>>(Wk, wqkvt + (size_t)NHC*CC, CC, KHC);
  trans_f2b<<<dim3(KHC/32, CC/32), tb, 0, stream>>>(Wv, wqkvt + (size_t)(NHC+KHC)*CC, CC, KHC);
  trans_f2b<<<dim3(NHC/32, NHC/32), tb, 0, stream>>>(Wo, wot, NHC, CC);
  sincos_init<<<(TT*64 + 255)/256, 256, 0, stream>>>(stab, ctab);
  gemm256<1><<<(BT/256) * (QKVC/256), 512, 0, stream>>>(xb, wqkvt, qkv, BT, QKVC, CC);
  postproc<<<BT, 256, 0, stream>>>(qkv, qrb, krb, stab, ctab);
  trans_v<<<dim3(TT/32, HD/32, BB*KVH), tb, 0, stream>>>(qkv, vTb);
  attn<<<BB * NHEAD * (TT/128), 256, 0, stream>>>(qrb, krb, vTb, encb);
  gemm256<0><<<(BT/256) * (CC/256), 512, 0, stream>>>(encb, wot, out, BT, CC, NHC);
}

// Round 8
// 498.945 us; speedup vs baseline: 1.0662x; 1.0436x over previous
//
#include <hip/hip_runtime.h>
#include <hip/hip_bf16.h>
#include <math.h>

typedef __attribute__((ext_vector_type(4))) float f32x4;
typedef __attribute__((ext_vector_type(16))) float f32x16;
typedef __attribute__((ext_vector_type(8))) short s16x8;
typedef __attribute__((ext_vector_type(4))) short s16x4;

#define BB 4
#define TT 2048
#define CC 2048
#define NHEAD 16
#define KVH 4
#define HD 128
#define BT (BB*TT)      // 8192
#define NHC 2048        // N*H
#define KHC 512         // K*H
#define QKVC 3072

__device__ __forceinline__ float bf2f(unsigned short u) {
  union { unsigned u; float f; } v; v.u = ((unsigned)u) << 16; return v.f;
}
__device__ __forceinline__ unsigned short f2bf(float f) {
  union { float f; unsigned u; } v; v.f = f;
  unsigned r = v.u + 0x7fff + ((v.u >> 16) & 1);
  return (unsigned short)(r >> 16);
}
// HW packed f32->bf16 (RTNE), src0 -> low half, src1 -> high half (T12 recipe)
__device__ __forceinline__ unsigned cvt_pk_bf16(float lo, float hi) {
  unsigned r;
  asm("v_cvt_pk_bf16_f32 %0, %1, %2" : "=v"(r) : "v"(lo), "v"(hi));
  return r;
}

#if defined(__has_builtin)
#if __has_builtin(__builtin_amdgcn_exp2f)
#define EXP2F(x) __builtin_amdgcn_exp2f(x)
#endif
#endif
#ifndef EXP2F
#define EXP2F(x) exp2f(x)
#endif

// ---- async global->LDS 16B (lane i lands at ldsbase + i*16; ldsbase must be wave-uniform) ----
__device__ __forceinline__ void glld16(const void* gsrc, void* ldsbase) {
  __builtin_amdgcn_global_load_lds(
      (const __attribute__((address_space(1))) unsigned int*)gsrc,
      (__attribute__((address_space(3))) unsigned int*)(unsigned int)(unsigned long long)ldsbase,
      16, 0, 0);
}

// ---------------- fp32 -> bf16 elementwise ----------------
__global__ void cvt_f2b(const float* __restrict__ in, unsigned short* __restrict__ out, int n4) {
  int i = blockIdx.x * 256 + threadIdx.x;
  if (i >= n4) return;
  float4 v = ((const float4*)in)[i];
  ushort4 o;
  o.x = f2bf(v.x); o.y = f2bf(v.y); o.z = f2bf(v.z); o.w = f2bf(v.w);
  ((ushort4*)out)[i] = o;
}

// ---------------- fp32 [R][Cc] -> bf16 [Cc][R] transpose ----------------
__global__ void trans_f2b(const float* __restrict__ in, unsigned short* __restrict__ out, int R, int Cc) {
  __shared__ float tile[32][33];
  int c0 = blockIdx.x * 32, r0 = blockIdx.y * 32;
  int tx = threadIdx.x, ty = threadIdx.y;
  #pragma unroll
  for (int k = 0; k < 4; k++)
    tile[ty + 8*k][tx] = in[(size_t)(r0 + ty + 8*k) * Cc + c0 + tx];
  __syncthreads();
  #pragma unroll
  for (int k = 0; k < 4; k++)
    out[(size_t)(c0 + ty + 8*k) * R + r0 + tx] = f2bf(tile[tx][ty + 8*k]);
}

// ---------------- V slice transpose bf16 [s][h] -> [h][s'] (PV-fragment-permuted s) ----
// Round-8: s-columns inside each 32-group are stored in PV fragment order so
// attn reads ONE ds_read_b128 per (su,hb) instead of 2x b64 + shuffle:
//   s = g*32 + half*16 + q*4 + rr   ->   s' = g*32 + q*8 + half*4 + rr
// (chunk cc = s'>>3 = g*4+q holds exactly vf = [half0 rr0-3 | half1 rr0-3]).
__global__ void trans_v(const unsigned short* __restrict__ qkv, unsigned short* __restrict__ vT) {
  __shared__ unsigned short tile[32][33];
  int slice = blockIdx.z;           // b*4+kh
  int s0 = blockIdx.x * 32, h0 = blockIdx.y * 32;
  int tx = threadIdx.x, ty = threadIdx.y;
  const unsigned short* in = qkv + (size_t)(slice >> 2) * TT * QKVC + (NHC + KHC) + (slice & 3) * HD;
  unsigned short* out = vT + (size_t)slice * HD * TT;
  int txp = ((tx >> 2) & 3) * 8 + ((tx >> 4) & 1) * 4 + (tx & 3);   // permuted s within 32
  #pragma unroll
  for (int k = 0; k < 4; k++)
    tile[ty + 8*k][tx] = in[(size_t)(s0 + ty + 8*k) * QKVC + h0 + tx];
  __syncthreads();
  #pragma unroll
  for (int k = 0; k < 4; k++)
    out[(size_t)(h0 + ty + 8*k) * TT + s0 + txp] = tile[tx][ty + 8*k];
}

// ---------------- RoPE sin/cos table (fp64 precision) ----------------
__global__ void sincos_init(float* __restrict__ stab, float* __restrict__ ctab) {
  int idx = blockIdx.x * 256 + threadIdx.x;
  if (idx >= TT * 64) return;
  int t = idx >> 6, i = idx & 63;
  double inv = exp(-log(10000.0) * ((double)i / 64.0));
  double ang = (double)t * inv;
  stab[idx] = (float)sin(ang);
  ctab[idx] = (float)cos(ang);
}

// ---------------- NT GEMM 256x256, BK=64, 8 waves, 32x32x16 MFMA (verified r7) ----------------
template<int OUTBF16>
__global__ __launch_bounds__(512, 2) void gemm256(
    const unsigned short* __restrict__ A, const unsigned short* __restrict__ Bt,
    void* __restrict__ outp, int M, int Nn, int Kd) {
  __shared__ unsigned short As[2][256 * 64];   // 32 KiB per buf
  __shared__ unsigned short Bs[2][256 * 64];
  int tid = threadIdx.x;
  int wave = tid >> 6, lane = tid & 63;
  int l32 = lane & 31, khf = lane >> 5;

  int gx = Nn >> 8;
  int nwg = gridDim.x;
  int bid = blockIdx.x;
  int bid2 = (nwg & 7) ? bid : ((bid & 7) * (nwg >> 3) + (bid >> 3));
  int bx = bid2 % gx, by = bid2 / gx;
  int m0 = by * 256, n0 = bx * 256;
  int wm = (wave >> 2) * 128, wn = (wave & 3) * 64;   // wave tile 128M x 64N

  f32x16 acc[4][2];
  #pragma unroll
  for (int i = 0; i < 4; i++)
    #pragma unroll
    for (int j = 0; j < 2; j++)
      #pragma unroll
      for (int r = 0; r < 16; r++) acc[i][j][r] = 0.f;

  const unsigned short* Abase = A + (size_t)m0 * Kd;
  const unsigned short* Bbase = Bt + (size_t)n0 * Kd;

  auto stage = [&](const unsigned short* Ak, const unsigned short* Bk, int buf) {
    #pragma unroll
    for (int t = 0; t < 4; t++) {
      int cf = (wave * 4 + t) * 64 + lane;
      int r = cf >> 3, cg = (cf & 7) ^ (r & 7);
      glld16(Ak + (size_t)r * Kd + cg * 8, &As[buf][(wave * 4 + t) * 512]);
    }
    #pragma unroll
    for (int t = 0; t < 4; t++) {
      int cf = (wave * 4 + t) * 64 + lane;
      int r = cf >> 3, cg = (cf & 7) ^ (r & 7);
      glld16(Bk + (size_t)r * Kd + cg * 8, &Bs[buf][(wave * 4 + t) * 512]);
    }
  };

  stage(Abase, Bbase, 0);
  __syncthreads();

  int nkt = Kd >> 6;
  for (int kt = 0; kt < nkt; kt++) {
    int cur = kt & 1;
    if (kt + 1 < nkt) stage(Abase + (kt + 1) * 64, Bbase + (kt + 1) * 64, cur ^ 1);
    #pragma unroll
    for (int ks = 0; ks < 4; ks++) {
      int c = ks * 2 + khf;
      s16x8 af[4], bfv[2];
      #pragma unroll
      for (int mf = 0; mf < 4; mf++) {
        int R = wm + mf * 32 + l32;
        af[mf] = *(const s16x8*)&As[cur][R * 64 + ((c ^ (R & 7)) << 3)];
      }
      #pragma unroll
      for (int nf = 0; nf < 2; nf++) {
        int R = wn + nf * 32 + l32;
        bfv[nf] = *(const s16x8*)&Bs[cur][R * 64 + ((c ^ (R & 7)) << 3)];
      }
      __builtin_amdgcn_s_setprio(1);
      #pragma unroll
      for (int mf = 0; mf < 4; mf++)
        #pragma unroll
        for (int nf = 0; nf < 2; nf++)
          acc[mf][nf] = __builtin_amdgcn_mfma_f32_32x32x16_bf16(af[mf], bfv[nf], acc[mf][nf], 0, 0, 0);
      __builtin_amdgcn_s_setprio(0);
    }
    __syncthreads();
  }

  #pragma unroll
  for (int mf = 0; mf < 4; mf++)
    #pragma unroll
    for (int nf = 0; nf < 2; nf++)
      #pragma unroll
      for (int r = 0; r < 16; r++) {
        int row = m0 + wm + mf * 32 + (r & 3) + 8 * (r >> 2) + 4 * khf;
        int col = n0 + wn + nf * 32 + l32;
        float v = acc[mf][nf][r];
        if (OUTBF16) ((unsigned short*)outp)[(size_t)row * Nn + col] = f2bf(v);
        else         ((float*)outp)[(size_t)row * Nn + col] = v;
      }
}

// ---------------- NT GEMM 256x128 (QKV): perfect grid packing (768 = 3x256) ----------------
// Round-8: the 256^2 QKV grid was 384 blocks = 1.5 dispatch waves on 256 CUs
// (75% packing). 256x128 tiles give 768 = 3 exact waves. Same staging swizzle,
// fragment map, and 32x32x16 MFMA as the verified gemm256; 4Mx2N wave layout.
template<int OUTBF16>
__global__ __launch_bounds__(512, 2) void gemm_qkv(
    const unsigned short* __restrict__ A, const unsigned short* __restrict__ Bt,
    void* __restrict__ outp, int M, int Nn, int Kd) {
  __shared__ unsigned short As[2][256 * 64];   // 32 KiB per buf
  __shared__ unsigned short Bs[2][128 * 64];   // 16 KiB per buf
  int tid = threadIdx.x;
  int wave = tid >> 6, lane = tid & 63;
  int l32 = lane & 31, khf = lane >> 5;

  int gx = Nn >> 7;
  int nwg = gridDim.x;
  int bid = blockIdx.x;
  int bid2 = (nwg & 7) ? bid : ((bid & 7) * (nwg >> 3) + (bid >> 3));
  int bx = bid2 % gx, by = bid2 / gx;
  int m0 = by * 256, n0 = bx * 128;
  int wm = (wave >> 1) * 64, wn = (wave & 1) * 64;   // wave tile 64M x 64N

  f32x16 acc[2][2];
  #pragma unroll
  for (int i = 0; i < 2; i++)
    #pragma unroll
    for (int j = 0; j < 2; j++)
      #pragma unroll
      for (int r = 0; r < 16; r++) acc[i][j][r] = 0.f;

  const unsigned short* Abase = A + (size_t)m0 * Kd;
  const unsigned short* Bbase = Bt + (size_t)n0 * Kd;

  auto stage = [&](const unsigned short* Ak, const unsigned short* Bk, int buf) {
    #pragma unroll
    for (int t = 0; t < 4; t++) {
      int cf = (wave * 4 + t) * 64 + lane;
      int r = cf >> 3, cg = (cf & 7) ^ (r & 7);
      glld16(Ak + (size_t)r * Kd + cg * 8, &As[buf][(wave * 4 + t) * 512]);
    }
    #pragma unroll
    for (int t = 0; t < 2; t++) {
      int cf = (wave * 2 + t) * 64 + lane;
      int r = cf >> 3, cg = (cf & 7) ^ (r & 7);
      glld16(Bk + (size_t)r * Kd + cg * 8, &Bs[buf][(wave * 2 + t) * 512]);
    }
  };

  stage(Abase, Bbase, 0);
  __syncthreads();

  int nkt = Kd >> 6;
  for (int kt = 0; kt < nkt; kt++) {
    int cur = kt & 1;
    if (kt + 1 < nkt) stage(Abase + (kt + 1) * 64, Bbase + (kt + 1) * 64, cur ^ 1);
    #pragma unroll
    for (int ks = 0; ks < 4; ks++) {
      int c = ks * 2 + khf;
      s16x8 af[2], bfv[2];
      #pragma unroll
      for (int mf = 0; mf < 2; mf++) {
        int R = wm + mf * 32 + l32;
        af[mf] = *(const s16x8*)&As[cur][R * 64 + ((c ^ (R & 7)) << 3)];
      }
      #pragma unroll
      for (int nf = 0; nf < 2; nf++) {
        int R = wn + nf * 32 + l32;
        bfv[nf] = *(const s16x8*)&Bs[cur][R * 64 + ((c ^ (R & 7)) << 3)];
      }
      __builtin_amdgcn_s_setprio(1);
      #pragma unroll
      for (int mf = 0; mf < 2; mf++)
        #pragma unroll
        for (int nf = 0; nf < 2; nf++)
          acc[mf][nf] = __builtin_amdgcn_mfma_f32_32x32x16_bf16(af[mf], bfv[nf], acc[mf][nf], 0, 0, 0);
      __builtin_amdgcn_s_setprio(0);
    }
    __syncthreads();
  }

  #pragma unroll
  for (int mf = 0; mf < 2; mf++)
    #pragma unroll
    for (int nf = 0; nf < 2; nf++)
      #pragma unroll
      for (int r = 0; r < 16; r++) {
        int row = m0 + wm + mf * 32 + (r & 3) + 8 * (r >> 2) + 4 * khf;
        int col = n0 + wn + nf * 32 + l32;
        float v = acc[mf][nf][r];
        if (OUTBF16) ((unsigned short*)outp)[(size_t)row * Nn + col] = f2bf(v);
        else         ((float*)outp)[(size_t)row * Nn + col] = v;
      }
}

// ---------------- RMSNorm + RoPE + scale ----------------
// NOTE: q scale folds in log2(e) so attention can use exp2 directly
// (softmax is exactly invariant: p = exp(S-m) = 2^(S*log2e - m*log2e)).
__global__ __launch_bounds__(256) void postproc(
    const unsigned short* __restrict__ qkv, unsigned short* __restrict__ qr,
    unsigned short* __restrict__ kr, const float* __restrict__ stab, const float* __restrict__ ctab) {
  __shared__ float sh[NHC + KHC];
  __shared__ float redq[4], redk[4];
  int row = blockIdx.x;
  int t = row & (TT - 1);
  int tid = threadIdx.x;
  const unsigned short* base = qkv + (size_t)row * QKVC;
  float sq = 0.f, sk = 0.f;
  uint4 qv = *(const uint4*)&base[tid * 8];
  const unsigned short* qp = (const unsigned short*)&qv;
  #pragma unroll
  for (int i = 0; i < 8; i++) { float f = bf2f(qp[i]); sh[tid*8 + i] = f; sq += f*f; }
  unsigned kv = *(const unsigned*)&base[NHC + tid*2];
  {
    float f0 = bf2f((unsigned short)(kv & 0xffff));
    float f1 = bf2f((unsigned short)(kv >> 16));
    sh[NHC + tid*2] = f0; sh[NHC + tid*2 + 1] = f1;
    sk += f0*f0 + f1*f1;
  }
  #pragma unroll
  for (int off = 32; off > 0; off >>= 1) { sq += __shfl_xor(sq, off); sk += __shfl_xor(sk, off); }
  if ((tid & 63) == 0) { redq[tid >> 6] = sq; redk[tid >> 6] = sk; }
  __syncthreads();
  float fq = rsqrtf((redq[0]+redq[1]+redq[2]+redq[3]) * (1.f/NHC) + 1e-6f)
             * (0.08838834764831845f * 1.4426950408889634f);
  float fk = rsqrtf((redk[0]+redk[1]+redk[2]+redk[3]) * (1.f/KHC) + 1e-6f);
  #pragma unroll
  for (int pi = 0; pi < 4; pi++) {
    int P = pi * 256 + tid;
    int head = P >> 6, i = P & 63;
    float s = stab[t*64 + i], c = ctab[t*64 + i];
    float x1 = sh[head*128 + i], x2 = sh[head*128 + i + 64];
    qr[(size_t)row * NHC + head*128 + i]      = f2bf((x1*c - x2*s) * fq);
    qr[(size_t)row * NHC + head*128 + i + 64] = f2bf((x2*c + x1*s) * fq);
  }
  {
    int head = tid >> 6, i = tid & 63;
    float s = stab[t*64 + i], c = ctab[t*64 + i];
    float x1 = sh[NHC + head*128 + i], x2 = sh[NHC + head*128 + i + 64];
    kr[(size_t)row * KHC + head*128 + i]      = f2bf((x1*c - x2*s) * fk);
    kr[(size_t)row * KHC + head*128 + i + 64] = f2bf((x2*c + x1*s) * fk);
  }
}

// ---------------- flash attention v6: v5 + single-b128 PV reads (permuted V) ----------------
__global__ __launch_bounds__(256, 2) void attn(
    const unsigned short* __restrict__ qr, const unsigned short* __restrict__ kr,
    const unsigned short* __restrict__ vT, unsigned short* __restrict__ enc) {
  __shared__ unsigned short Ks[2][64 * 128];   // 16KB each; Ks[0]+Ks[1] holds Q in prologue
  __shared__ unsigned short Vs[2][128 * 64];   // 16KB each, layout [h][s'-chunk] (permuted s)
  int tid = threadIdx.x;
  int wave = tid >> 6, lane = tid & 63, q4 = lane >> 4, l16 = lane & 15;
  int bid = blockIdx.x;
  int qt = bid & 15, n = (bid >> 4) & 15, b = bid >> 8, kh = n >> 2;

  const unsigned short* kbase = kr + ((size_t)(b * TT)) * KHC + kh * HD;
  const unsigned short* vbase = vT + ((size_t)((b * KVH + kh) * HD)) * TT;

  auto stageK = [&](int j, int kb) {
    const unsigned short* base = kbase + (size_t)(j * 64) * KHC;
    #pragma unroll
    for (int t = 0; t < 4; t++) {
      int L = wave * 4 + t;
      int r = L * 4 + (lane >> 4);
      int cg = (lane & 15) ^ (r & 7);
      glld16(base + (size_t)r * KHC + cg * 8, &Ks[kb][L * 512]);
    }
  };
  auto stageV = [&](int j, int vb) {
    const unsigned short* base = vbase + j * 64;
    #pragma unroll
    for (int t = 0; t < 4; t++) {
      int L = wave * 4 + t;
      int r = L * 8 + (lane >> 3);
      int cg = (lane & 7) ^ (r & 7);
      glld16(base + (size_t)r * TT + cg * 8, &Vs[vb][L * 512]);
    }
  };

  {
    const unsigned short* base = qr + ((size_t)(b * TT + qt * 128)) * NHC + n * HD;
    #pragma unroll
    for (int t = 0; t < 8; t++) {
      int L = wave * 8 + t;
      int r = L * 4 + (lane >> 4);
      int cg = (lane & 15) ^ (r & 7);
      glld16(base + (size_t)r * NHC + cg * 8, (unsigned short*)Ks + L * 512);
    }
  }
  stageV(0, 0);
  asm volatile("s_waitcnt vmcnt(0)" ::: "memory");
  __syncthreads();
  s16x8 qf[2][4];
  #pragma unroll
  for (int qb = 0; qb < 2; qb++)
    #pragma unroll
    for (int ku = 0; ku < 4; ku++) {
      int r = wave * 32 + qb * 16 + l16;
      qf[qb][ku] = *(const s16x8*)&((const unsigned short*)Ks)[r * 128 + (((ku * 4 + q4) ^ (r & 7)) << 3)];
    }
  __syncthreads();
  stageK(0, 0);
  asm volatile("s_waitcnt vmcnt(0)" ::: "memory");
  __syncthreads();

  float m_st[2] = {-1e30f, -1e30f}, l_st[2] = {0.f, 0.f};
  f32x4 O[2][8];
  #pragma unroll
  for (int qb = 0; qb < 2; qb++)
    #pragma unroll
    for (int hb = 0; hb < 8; hb++) O[qb][hb] = f32x4{0.f, 0.f, 0.f, 0.f};

  for (int j = 0; j < 32; j++) {
    int cur = j & 1;
    if (j < 31) { stageK(j + 1, cur ^ 1); stageV(j + 1, cur ^ 1); }
    f32x4 S[2][4];
    #pragma unroll
    for (int qb = 0; qb < 2; qb++)
      #pragma unroll
      for (int mb = 0; mb < 4; mb++) S[qb][mb] = f32x4{0.f, 0.f, 0.f, 0.f};
    __builtin_amdgcn_s_setprio(1);
    #pragma unroll
    for (int mb = 0; mb < 4; mb++) {
      int r = mb * 16 + l16;
      #pragma unroll
      for (int ku = 0; ku < 4; ku++) {
        s16x8 kf = *(const s16x8*)&Ks[cur][r * 128 + (((ku * 4 + q4) ^ (r & 7)) << 3)];
        S[0][mb] = __builtin_amdgcn_mfma_f32_16x16x32_bf16(kf, qf[0][ku], S[0][mb], 0, 0, 0);
        S[1][mb] = __builtin_amdgcn_mfma_f32_16x16x32_bf16(kf, qf[1][ku], S[1][mb], 0, 0, 0);
      }
    }
    __builtin_amdgcn_s_setprio(0);
    s16x8 pf8[2][2];
    #pragma unroll
    for (int qb = 0; qb < 2; qb++) {
      float mx = -1e30f;
      #pragma unroll
      for (int mb = 0; mb < 4; mb++)
        #pragma unroll
        for (int r = 0; r < 4; r++) mx = fmaxf(mx, S[qb][mb][r]);
      mx = fmaxf(mx, __shfl_xor(mx, 16));
      mx = fmaxf(mx, __shfl_xor(mx, 32));
      if (!__all(mx - m_st[qb] <= 8.f)) {
        float alpha = EXP2F(m_st[qb] - mx);
        m_st[qb] = mx;
        l_st[qb] *= alpha;
        #pragma unroll
        for (int hb = 0; hb < 8; hb++) O[qb][hb] *= alpha;
      }
      float mcur = m_st[qb];
      float rs = 0.f;
      #pragma unroll
      for (int su = 0; su < 2; su++) {
        union { s16x8 v; unsigned d[4]; } pu;
        #pragma unroll
        for (int hf = 0; hf < 2; hf++) {
          int mb = su * 2 + hf;
          float p0 = EXP2F(S[qb][mb][0] - mcur);
          float p1 = EXP2F(S[qb][mb][1] - mcur);
          float p2 = EXP2F(S[qb][mb][2] - mcur);
          float p3 = EXP2F(S[qb][mb][3] - mcur);
          rs += (p0 + p1) + (p2 + p3);
          pu.d[hf * 2 + 0] = cvt_pk_bf16(p0, p1);
          pu.d[hf * 2 + 1] = cvt_pk_bf16(p2, p3);
        }
        pf8[qb][su] = pu.v;
      }
      rs += __shfl_xor(rs, 16);
      rs += __shfl_xor(rs, 32);
      l_st[qb] += rs;
    }
    // ---- PV: single b128 per (su,hb) thanks to permuted V layout ----
    __builtin_amdgcn_s_setprio(1);
    #pragma unroll
    for (int su = 0; su < 2; su++) {
      #pragma unroll
      for (int hb = 0; hb < 8; hb++) {
        int r = hb * 16 + l16;
        s16x8 vf = *(const s16x8*)&Vs[cur][r * 64 + (((su * 4 + q4) ^ (r & 7)) << 3)];
        O[0][hb] = __builtin_amdgcn_mfma_f32_16x16x32_bf16(vf, pf8[0][su], O[0][hb], 0, 0, 0);
        O[1][hb] = __builtin_amdgcn_mfma_f32_16x16x32_bf16(vf, pf8[1][su], O[1][hb], 0, 0, 0);
      }
    }
    __builtin_amdgcn_s_setprio(0);
    asm volatile("s_waitcnt vmcnt(0)" ::: "memory");
    __syncthreads();
  }
  #pragma unroll
  for (int qb = 0; qb < 2; qb++) {
    float inv = 1.f / l_st[qb];
    int t = b * TT + qt * 128 + wave * 32 + qb * 16 + l16;
    #pragma unroll
    for (int hb = 0; hb < 8; hb++) {
      union { ushort4 s; unsigned d[2]; } o;
      o.d[0] = cvt_pk_bf16(O[qb][hb][0] * inv, O[qb][hb][1] * inv);
      o.d[1] = cvt_pk_bf16(O[qb][hb][2] * inv, O[qb][hb][3] * inv);
      *(ushort4*)&enc[(size_t)t * NHC + n * HD + hb * 16 + q4 * 4] = o.s;
    }
  }
}

extern "C" void kernel_launch(void* const* d_in, const int* in_sizes, int n_in,
                              void* d_out, int out_size, void* d_ws, size_t ws_size,
                              hipStream_t stream) {
  const float* x  = (const float*)d_in[0];
  const float* Wq = (const float*)d_in[1];
  const float* Wk = (const float*)d_in[2];
  const float* Wv = (const float*)d_in[3];
  const float* Wo = (const float*)d_in[4];
  float* out = (float*)d_out;

  char* ws = (char*)d_ws;
  size_t off = 0;
  auto alloc = [&](size_t bytes) -> void* {
    void* p = ws + off;
    off += (bytes + 255) & ~(size_t)255;
    return p;
  };
  unsigned short* xb    = (unsigned short*)alloc((size_t)BT * CC * 2);
  unsigned short* wqkvt = (unsigned short*)alloc((size_t)QKVC * CC * 2);
  unsigned short* wot   = (unsigned short*)alloc((size_t)CC * NHC * 2);
  unsigned short* qkv   = (unsigned short*)alloc((size_t)BT * QKVC * 2);
  unsigned short* qrb   = (unsigned short*)alloc((size_t)BT * NHC * 2);
  unsigned short* krb   = (unsigned short*)alloc((size_t)BT * KHC * 2);
  unsigned short* vTb   = (unsigned short*)alloc((size_t)BB * KVH * HD * TT * 2);
  unsigned short* encb  = (unsigned short*)alloc((size_t)BT * NHC * 2);
  float* stab = (float*)alloc((size_t)TT * 64 * 4);
  float* ctab = (float*)alloc((size_t)TT * 64 * 4);

  dim3 tb(32, 8);
  cvt_f2b<<<(BT*CC/4 + 255)/256, 256, 0, stream>>>(x, xb, BT*CC/4);
  trans_f2b<<<dim3(NHC/32, CC/32), tb, 0, stream>>>(Wq, wqkvt, CC, NHC);
  trans_f2b<<<dim3(KHC/32, CC/32), tb, 0, stream>>>(Wk, wqkvt + (size_t)NHC*CC, CC, KHC);
  trans_f2b<<<dim3(KHC/32, CC/32), tb, 0, stream>>>(Wv, wqkvt + (size_t)(NHC+KHC)*CC, CC, KHC);
  trans_f2b<<<dim3(NHC/32, NHC/32), tb, 0, stream>>>(Wo, wot, NHC, CC);
  sincos_init<<<(TT*64 + 255)/256, 256, 0, stream>>>(stab, ctab);
  gemm_qkv<1><<<(BT/256) * (QKVC/128), 512, 0, stream>>>(xb, wqkvt, qkv, BT, QKVC, CC);
  postproc<<<BT, 256, 0, stream>>>(qkv, qrb, krb, stab, ctab);
  trans_v<<<dim3(TT/32, HD/32, BB*KVH), tb, 0, stream>>>(qkv, vTb);
  attn<<<BB * NHEAD * (TT/128), 256, 0, stream>>>(qrb, krb, vTb, encb);
  gemm256<0><<<(BT/256) * (CC/256), 512, 0, stream>>>(encb, wot, out, BT, CC, NHC);
}